// Round 7
// baseline (416.949 us; speedup 1.0000x reference)
//
#include <hip/hip_runtime.h>
#include <cstdint>
#include <cstddef>

// Problem constants
#define B_    8
#define S_    2048
#define DM_   512
#define H_    8
#define SD_   64
#define HID_  2048
#define ROWS  (B_*S_)      // 16384
#define BH    (B_*H_)      // 64
#define NCHUNK 32
#define CLEN   64
#define EPS_  1e-5f
#define PLANE ((size_t)ROWS*64)   // one head-plane of proj: 16384*64 shorts

typedef __bf16 bf16x8 __attribute__((ext_vector_type(8)));
typedef float  floatx4 __attribute__((ext_vector_type(4)));

// proj layout is HEAD-MAJOR: proj[plane][row][64], plane = mat*8 + h,
// mat: 0=a(tanh), 1=b(tanh), 2=ql(tanh), 3=qr(tanh); row = b*S+t.
// Gate layout is HEAD-MAJOR too: sdo/pdo[h][ROWS] (coalesced t-runs for scan readers).

// ---------- small helpers ----------
static __device__ __forceinline__ float bf2f(unsigned short h){
  union { unsigned int u; float f; } v; v.u = ((unsigned int)h) << 16; return v.f;
}
static __device__ __forceinline__ unsigned short f2bf(float f){
  union { float f; unsigned int u; } v; v.f = f;
  unsigned int r = v.u + 0x7fffu + ((v.u >> 16) & 1u);
  return (unsigned short)(r >> 16);
}
static __device__ __forceinline__ float fast_tanh(float x){
  float ax = fabsf(x);
  float e  = __expf(2.f*ax);
  float t  = 1.f - 2.f/(e+1.f);
  return copysignf(t, x);
}
static __device__ __forceinline__ float sigmoidf_(float z){
  return 1.f/(1.f + expf(-z));
}
static __device__ __forceinline__ float gelu_exact(float x){
  return 0.5f*x*(1.f + erff(x*0.70710678118654752440f));
}
static __device__ __forceinline__ void gld_lds16(const unsigned short* g, unsigned short* lds){
  __builtin_amdgcn_global_load_lds(
      (const __attribute__((address_space(1))) void*)g,
      (__attribute__((address_space(3))) void*)lds,
      16, 0, 0);
}
// XOR swizzle for 64-half (128B) rows: 16B chunk kc of row r stored at chunk kc^(r&7)
static __device__ __forceinline__ int swz(int row, int col){
  return row*64 + (((col>>3) ^ (row&7))<<3) + (col&7);
}

// ---------- weight fp32 -> bf16 conversion ----------
__global__ __launch_bounds__(256) void cvt_weights(
    const float* __restrict__ wa, const float* __restrict__ wb,
    const float* __restrict__ wql, const float* __restrict__ wqr,
    const float* __restrict__ wout, const float* __restrict__ w1,
    const float* __restrict__ w2,
    unsigned short* __restrict__ wcat, unsigned short* __restrict__ woutb,
    unsigned short* __restrict__ w1b, unsigned short* __restrict__ w2b){
  int i = blockIdx.x*256 + threadIdx.x;   // float4 units, total 851968
  const float* s; unsigned short* d; int base;
  if      (i <  65536){ s=wa;   d=wcat;          base=i; }
  else if (i < 131072){ s=wb;   d=wcat+262144;   base=i-65536; }
  else if (i < 196608){ s=wql;  d=wcat+524288;   base=i-131072; }
  else if (i < 262144){ s=wqr;  d=wcat+786432;   base=i-196608; }
  else if (i < 327680){ s=wout; d=woutb;         base=i-262144; }
  else if (i < 589824){ s=w1;   d=w1b;           base=i-327680; }
  else                { s=w2;   d=w2b;           base=i-589824; }
  float4 v = ((const float4*)s)[base];
  ushort4 o; o.x=f2bf(v.x); o.y=f2bf(v.y); o.z=f2bf(v.z); o.w=f2bf(v.w);
  ((ushort4*)d)[base] = o;
}

// ---------- LN1 + gate heads (4 rows/block, 1 wave each) ----------
__global__ __launch_bounds__(256) void ln_gates(
    const float* __restrict__ x, const float* __restrict__ gam, const float* __restrict__ bet,
    const float* __restrict__ Wsd, const float* __restrict__ bsd,
    const float* __restrict__ Wpd, const float* __restrict__ bpd,
    unsigned short* __restrict__ nbf, float* __restrict__ sdo, float* __restrict__ pdo){
  const int row = blockIdx.x*4 + (threadIdx.x>>6), l = threadIdx.x & 63;
  const float* xr = x + (size_t)row*DM_;
  float4 v0 = ((const float4*)xr)[l*2];
  float4 v1 = ((const float4*)xr)[l*2+1];
  float v[8] = {v0.x,v0.y,v0.z,v0.w,v1.x,v1.y,v1.z,v1.w};
  float s = 0.f;
  #pragma unroll
  for (int i=0;i<8;++i) s += v[i];
  #pragma unroll
  for (int m=1;m<64;m<<=1) s += __shfl_xor(s, m);
  const float mean = s * (1.f/512.f);
  float q = 0.f;
  #pragma unroll
  for (int i=0;i<8;++i){ float d = v[i]-mean; q += d*d; }
  #pragma unroll
  for (int m=1;m<64;m<<=1) q += __shfl_xor(q, m);
  const float rstd = rsqrtf(q*(1.f/512.f) + EPS_);
  float4 g0 = ((const float4*)gam)[l*2], g1 = ((const float4*)gam)[l*2+1];
  float4 b0 = ((const float4*)bet)[l*2], b1 = ((const float4*)bet)[l*2+1];
  float gg[8] = {g0.x,g0.y,g0.z,g0.w,g1.x,g1.y,g1.z,g1.w};
  float bb[8] = {b0.x,b0.y,b0.z,b0.w,b1.x,b1.y,b1.z,b1.w};
  float n[8];
  #pragma unroll
  for (int i=0;i<8;++i) n[i] = (v[i]-mean)*rstd*gg[i] + bb[i];
  ushort4 o0, o1;
  o0.x=f2bf(n[0]); o0.y=f2bf(n[1]); o0.z=f2bf(n[2]); o0.w=f2bf(n[3]);
  o1.x=f2bf(n[4]); o1.y=f2bf(n[5]); o1.z=f2bf(n[6]); o1.w=f2bf(n[7]);
  ((ushort4*)(nbf + (size_t)row*DM_))[l*2]   = o0;
  ((ushort4*)(nbf + (size_t)row*DM_))[l*2+1] = o1;
  float acc[16];
  #pragma unroll
  for (int hh=0; hh<8; ++hh){
    const float4* ws = (const float4*)(Wsd + hh*DM_) + l*2;
    const float4* wp = (const float4*)(Wpd + hh*DM_) + l*2;
    float4 a0=ws[0], a1=ws[1], p0=wp[0], p1=wp[1];
    acc[hh]   = n[0]*a0.x+n[1]*a0.y+n[2]*a0.z+n[3]*a0.w+n[4]*a1.x+n[5]*a1.y+n[6]*a1.z+n[7]*a1.w;
    acc[8+hh] = n[0]*p0.x+n[1]*p0.y+n[2]*p0.z+n[3]*p0.w+n[4]*p1.x+n[5]*p1.y+n[6]*p1.z+n[7]*p1.w;
  }
  #pragma unroll
  for (int k=0;k<16;++k){
    float a = acc[k];
    #pragma unroll
    for (int m=1;m<64;m<<=1) a += __shfl_xor(a, m);
    acc[k] = a;
  }
  if (l==0){
    #pragma unroll
    for (int hh=0; hh<8; ++hh){
      sdo[(size_t)hh*ROWS + row] = sigmoidf_(acc[hh]   + bsd[hh]);
      pdo[(size_t)hh*ROWS + row] = sigmoidf_(acc[8+hh] + bpd[hh]);
    }
  }
}

// ---------- plain LN (FFN), bf16 input (4 rows/block) ----------
__global__ __launch_bounds__(256) void ln_plain(
    const unsigned short* __restrict__ xb, const float* __restrict__ gam, const float* __restrict__ bet,
    unsigned short* __restrict__ ob){
  const int row = blockIdx.x*4 + (threadIdx.x>>6), l = threadIdx.x & 63;
  const unsigned short* xr = xb + (size_t)row*DM_ + l*8;
  ushort4 u0 = *(const ushort4*)xr;
  ushort4 u1 = *(const ushort4*)(xr+4);
  float v[8] = {bf2f(u0.x),bf2f(u0.y),bf2f(u0.z),bf2f(u0.w),
                bf2f(u1.x),bf2f(u1.y),bf2f(u1.z),bf2f(u1.w)};
  float s = 0.f;
  #pragma unroll
  for (int i=0;i<8;++i) s += v[i];
  #pragma unroll
  for (int m=1;m<64;m<<=1) s += __shfl_xor(s, m);
  const float mean = s * (1.f/512.f);
  float q = 0.f;
  #pragma unroll
  for (int i=0;i<8;++i){ float d = v[i]-mean; q += d*d; }
  #pragma unroll
  for (int m=1;m<64;m<<=1) q += __shfl_xor(q, m);
  const float rstd = rsqrtf(q*(1.f/512.f) + EPS_);
  float4 g0 = ((const float4*)gam)[l*2], g1 = ((const float4*)gam)[l*2+1];
  float4 b0 = ((const float4*)bet)[l*2], b1 = ((const float4*)bet)[l*2+1];
  float gg[8] = {g0.x,g0.y,g0.z,g0.w,g1.x,g1.y,g1.z,g1.w};
  float bb[8] = {b0.x,b0.y,b0.z,b0.w,b1.x,b1.y,b1.z,b1.w};
  ushort4 o0, o1;
  o0.x=f2bf((v[0]-mean)*rstd*gg[0]+bb[0]); o0.y=f2bf((v[1]-mean)*rstd*gg[1]+bb[1]);
  o0.z=f2bf((v[2]-mean)*rstd*gg[2]+bb[2]); o0.w=f2bf((v[3]-mean)*rstd*gg[3]+bb[3]);
  o1.x=f2bf((v[4]-mean)*rstd*gg[4]+bb[4]); o1.y=f2bf((v[5]-mean)*rstd*gg[5]+bb[5]);
  o1.z=f2bf((v[6]-mean)*rstd*gg[6]+bb[6]); o1.w=f2bf((v[7]-mean)*rstd*gg[7]+bb[7]);
  ((ushort4*)(ob + (size_t)row*DM_))[l*2]   = o0;
  ((ushort4*)(ob + (size_t)row*DM_))[l*2+1] = o1;
}

// ---------- 128x128-tile GEMM, BK=64, single-buffered (measured-best for N=2048 GEMMs) ----------
// MODE 0: tanh -> bf16 HEAD-MAJOR planes (proj); 2: +bias,gelu -> bf16
template<int MODE>
__global__ __launch_bounds__(256) void gemm128(
    const unsigned short* __restrict__ A, const unsigned short* __restrict__ W,
    const float* __restrict__ bias, const float* __restrict__ residf,
    const unsigned short* __restrict__ residb,
    float* __restrict__ outf, unsigned short* __restrict__ outb,
    int N, int K){
  __shared__ __align__(16) unsigned short As[128*64];
  __shared__ __align__(16) unsigned short Ws[128*64];
  const int tid  = threadIdx.x;
  const int w    = tid >> 6;
  const int lane = tid & 63;
  const int mblk = blockIdx.x, nblk = blockIdx.y;
  const int mrow = (w >> 1) * 64;
  const int ncol = (w & 1) * 64;
  const int fr = lane & 15, fq = lane >> 4;

  int srow[4], scol[4];
  #pragma unroll
  for (int q=0;q<4;++q){
    const int p = q*256 + w*64 + lane;
    srow[q] = p >> 3;
    scol[q] = ((p & 7) ^ (srow[q] & 7)) * 8;
  }

  floatx4 acc[4][4];
  #pragma unroll
  for (int i=0;i<4;++i)
    #pragma unroll
    for (int j=0;j<4;++j)
      acc[i][j] = (floatx4){0.f,0.f,0.f,0.f};

  for (int k0=0; k0<K; k0+=64){
    #pragma unroll
    for (int q=0;q<4;++q){
      gld_lds16(A + (size_t)(mblk*128 + srow[q])*K + k0 + scol[q], As + (q*256 + w*64)*8);
      gld_lds16(W + (size_t)(nblk*128 + srow[q])*K + k0 + scol[q], Ws + (q*256 + w*64)*8);
    }
    __syncthreads();
    #pragma unroll
    for (int kh=0;kh<2;++kh){
      bf16x8 af[4], bf[4];
      #pragma unroll
      for (int i=0;i<4;++i) af[i] = *(const bf16x8*)&As[swz(mrow + i*16 + fr, kh*32 + fq*8)];
      #pragma unroll
      for (int j=0;j<4;++j) bf[j] = *(const bf16x8*)&Ws[swz(ncol + j*16 + fr, kh*32 + fq*8)];
      #pragma unroll
      for (int i=0;i<4;++i)
        #pragma unroll
        for (int j=0;j<4;++j)
          acc[i][j] = __builtin_amdgcn_mfma_f32_16x16x32_bf16(af[i], bf[j], acc[i][j], 0, 0, 0);
    }
    __syncthreads();
  }

  #pragma unroll
  for (int i=0;i<4;++i){
    const int grow_base = mblk*128 + mrow + i*16 + fq*4;
    #pragma unroll
    for (int j=0;j<4;++j){
      const int gcol = nblk*128 + ncol + j*16 + fr;
      float bias_v = 0.f;
      if (MODE==2 || MODE==3) bias_v = bias[gcol];
      #pragma unroll
      for (int r=0;r<4;++r){
        float v = acc[i][j][r];
        if (MODE==0){
          // head-major plane write: plane = gcol>>6, in-plane col = gcol&63
          const size_t o = (size_t)(gcol>>6)*PLANE + (size_t)(grow_base + r)*64 + (gcol & 63);
          outb[o] = f2bf(fast_tanh(v));
        } else {
          const size_t o = (size_t)(grow_base + r)*N + gcol;
          if      (MODE==1) outb[o] = f2bf(residf[o] + v);
          else if (MODE==2) outb[o] = f2bf(gelu_exact(v + bias_v));
          else              outf[o] = bf2f(residb[o]) + v + bias_v;
        }
      }
    }
  }
}

// ---------- 64x128-tile GEMM, BK=64 (for N=512 GEMMs: 1024 blocks -> 4 blocks/CU) ----------
// Same swizzle, same MFMA density (16/K-step/wave), same per-element accumulation
// order as gemm128 -> bitwise-identical outputs. 4 waves, each 64 rows x 32 cols.
// MODE 1: +resid(f32) -> bf16; 3: +bias+resid(bf16) -> f32
template<int MODE>
__global__ __launch_bounds__(256) void gemm64(
    const unsigned short* __restrict__ A, const unsigned short* __restrict__ W,
    const float* __restrict__ bias, const float* __restrict__ residf,
    const unsigned short* __restrict__ residb,
    float* __restrict__ outf, unsigned short* __restrict__ outb,
    int N, int K){
  __shared__ __align__(16) unsigned short As[64*64];    // 8 KB
  __shared__ __align__(16) unsigned short Ws[128*64];   // 16 KB
  const int tid  = threadIdx.x;
  const int w    = tid >> 6;          // wave 0..3
  const int lane = tid & 63;
  const int mblk = blockIdx.x, nblk = blockIdx.y;
  const int ncol = w * 32;            // wave's col base within the 128-wide tile
  const int fr = lane & 15, fq = lane >> 4;

  int srA[2], scA[2];                 // A: 64x64 = 512 16B-chunks / 256 thr = 2 each
  #pragma unroll
  for (int q=0;q<2;++q){
    const int p = q*256 + tid;
    srA[q] = p >> 3;
    scA[q] = ((p & 7) ^ (srA[q] & 7)) * 8;
  }
  int srW[4], scW[4];                 // W: 128x64 = 1024 chunks / 256 thr = 4 each
  #pragma unroll
  for (int q=0;q<4;++q){
    const int p = q*256 + tid;
    srW[q] = p >> 3;
    scW[q] = ((p & 7) ^ (srW[q] & 7)) * 8;
  }

  floatx4 acc[4][2];
  #pragma unroll
  for (int i=0;i<4;++i)
    #pragma unroll
    for (int j=0;j<2;++j)
      acc[i][j] = (floatx4){0.f,0.f,0.f,0.f};

  for (int k0=0; k0<K; k0+=64){
    #pragma unroll
    for (int q=0;q<2;++q)
      gld_lds16(A + (size_t)(mblk*64 + srA[q])*K + k0 + scA[q], As + (q*256 + tid)*8);
    #pragma unroll
    for (int q=0;q<4;++q)
      gld_lds16(W + (size_t)(nblk*128 + srW[q])*K + k0 + scW[q], Ws + (q*256 + tid)*8);
    __syncthreads();
    #pragma unroll
    for (int kh=0;kh<2;++kh){
      bf16x8 af[4], bf[2];
      #pragma unroll
      for (int i=0;i<4;++i) af[i] = *(const bf16x8*)&As[swz(i*16 + fr, kh*32 + fq*8)];
      #pragma unroll
      for (int j=0;j<2;++j) bf[j] = *(const bf16x8*)&Ws[swz(ncol + j*16 + fr, kh*32 + fq*8)];
      #pragma unroll
      for (int i=0;i<4;++i)
        #pragma unroll
        for (int j=0;j<2;++j)
          acc[i][j] = __builtin_amdgcn_mfma_f32_16x16x32_bf16(af[i], bf[j], acc[i][j], 0, 0, 0);
    }
    __syncthreads();
  }

  #pragma unroll
  for (int i=0;i<4;++i){
    const int grow_base = mblk*64 + i*16 + fq*4;
    #pragma unroll
    for (int j=0;j<2;++j){
      const int gcol = nblk*128 + ncol + j*16 + fr;
      float bias_v = 0.f;
      if (MODE==3) bias_v = bias[gcol];
      #pragma unroll
      for (int r=0;r<4;++r){
        const size_t o = (size_t)(grow_base + r)*N + gcol;
        float v = acc[i][j][r];
        if (MODE==1) outb[o] = f2bf(residf[o] + v);
        else         outf[o] = bf2f(residb[o]) + v + bias_v;
      }
    }
  }
}

// ---------- state scan, chunk-local (LDS-staged; bf16 sloc + f32 chunk ends) ----------
__global__ __launch_bounds__(64) void state_local(
    const unsigned short* __restrict__ proj, const float* __restrict__ sdo,
    unsigned short* __restrict__ slocb, float* __restrict__ Sarr,
    float* __restrict__ sEnd){
  __shared__ __align__(16) unsigned short a_s[4096];
  __shared__ float sv_s[64];
  const int c = blockIdx.x, bh = blockIdx.y, b = bh>>3, h = bh&7, d = threadIdx.x;
  const int t0 = c*CLEN;
  // cooperative stage: 8 KB contiguous (64 t x 64 d) via float4 (16B) chunks
  const unsigned short* ap = proj + (size_t)h*PLANE + (size_t)(b*S_+t0)*64;
  #pragma unroll
  for (int q=0;q<8;++q)
    *(float4*)&a_s[(q*64 + d)*8] = *(const float4*)(ap + (size_t)(q*64 + d)*8);
  sv_s[d] = sdo[(size_t)h*ROWS + b*S_+t0+d];
  __syncthreads();
  float s = 0.f, S = 1.f;
  #pragma unroll 4
  for (int j=0;j<CLEN;++j){
    const int t = t0 + j;
    float a  = bf2f(a_s[j*64 + d]);
    float sv = sv_s[j];
    s = sv*s + (1.f-sv)*a;
    S *= sv;
    slocb[((size_t)bh*S_ + t)*64 + d] = f2bf(s);
    if (d==0) Sarr[bh*S_ + t] = S;
  }
  sEnd[((size_t)c*BH + bh)*64 + d] = s;
}

__global__ __launch_bounds__(64) void state_combine(
    const float* __restrict__ sEnd, const float* __restrict__ Sarr,
    float* __restrict__ sinit){
  const int bh = blockIdx.x, d = threadIdx.x;
  float acc = 0.f;
  for (int c=0;c<NCHUNK;++c){
    sinit[((size_t)c*BH + bh)*64 + d] = acc;
    const int te = c*CLEN + CLEN - 1;
    acc = Sarr[bh*S_ + te]*acc + sEnd[((size_t)c*BH + bh)*64 + d];
  }
}

// ---------- pair chunk-local sums via MFMA (prev computed inline) ----------
__global__ __launch_bounds__(64) void pair_localm(
    const unsigned short* __restrict__ proj, const float* __restrict__ pdo,
    const unsigned short* __restrict__ slocb, const float* __restrict__ Sarr,
    const float* __restrict__ sinit, float* __restrict__ pairbuf,
    float* __restrict__ Dprod){
  __shared__ __align__(16) unsigned short Bt[4096];
  __shared__ __align__(16) unsigned short Pt[4096];
  const int c=blockIdx.x, bh=blockIdx.y, b=bh>>3, h=bh&7, l=threadIdx.x;
  const int t = c*CLEN + l;
  float pd = pdo[(size_t)h*ROWS + b*S_+t];
  float D = pd;
  #pragma unroll
  for (int m=1;m<64;m<<=1){ float o = __shfl_up(D, m); if (l>=m) D *= o; }
  const float Dend = __shfl(D, 63);
  const float cu = (Dend / D) * (1.f - pd);
  if (l==63) Dprod[c*BH+bh] = Dend;
  {
    const unsigned short* brow = proj + (size_t)(8+h)*PLANE + (size_t)(b*S_+t)*64;
    const size_t ptm = (size_t)bh*S_ + (l==0 ? t : t-1);   // clamped (values unused when l==0)
    const unsigned short* srow = slocb + ptm*64;
    const float* initp = sinit + ((size_t)c*BH + bh)*64;
    float sp = 0.f;
    if (l>0) sp = Sarr[ptm];
    #pragma unroll
    for (int e8=0;e8<8;++e8){
      ushort4 u0 = *(const ushort4*)(brow + e8*8);
      ushort4 u1 = *(const ushort4*)(brow + e8*8 + 4);
      unsigned short vs[8] = {u0.x,u0.y,u0.z,u0.w,u1.x,u1.y,u1.z,u1.w};
      ushort4 s0 = *(const ushort4*)(srow + e8*8);
      ushort4 s1 = *(const ushort4*)(srow + e8*8 + 4);
      unsigned short ss[8] = {s0.x,s0.y,s0.z,s0.w,s1.x,s1.y,s1.z,s1.w};
      float4 i0 = *(const float4*)(initp + e8*8);
      float4 i1 = *(const float4*)(initp + e8*8 + 4);
      float iv[8] = {i0.x,i0.y,i0.z,i0.w,i1.x,i1.y,i1.z,i1.w};
      #pragma unroll
      for (int q=0;q<8;++q){
        const int r = e8*8+q;
        float p = (l==0) ? iv[q] : (sp*iv[q] + bf2f(ss[q]));
        Bt[swz(r, l)] = f2bf(cu * bf2f(vs[q]));
        Pt[swz(r, l)] = f2bf(p);
      }
    }
  }
  __syncthreads();
  const int fr = l & 15, fq = l >> 4;
  floatx4 acc[4][4];
  #pragma unroll
  for (int i=0;i<4;++i)
    #pragma unroll
    for (int j=0;j<4;++j) acc[i][j] = (floatx4){0.f,0.f,0.f,0.f};
  #pragma unroll
  for (int kh=0;kh<2;++kh){
    bf16x8 af[4], bfr[4];
    #pragma unroll
    for (int i=0;i<4;++i) af[i]  = *(const bf16x8*)&Bt[swz(i*16+fr, kh*32+fq*8)];
    #pragma unroll
    for (int j=0;j<4;++j) bfr[j] = *(const bf16x8*)&Pt[swz(j*16+fr, kh*32+fq*8)];
    #pragma unroll
    for (int i=0;i<4;++i)
      #pragma unroll
      for (int j=0;j<4;++j)
        acc[i][j] = __builtin_amdgcn_mfma_f32_16x16x32_bf16(af[i], bfr[j], acc[i][j], 0, 0, 0);
  }
  float* outp = pairbuf + ((size_t)c*BH + bh)*4096;
  #pragma unroll
  for (int i=0;i<4;++i)
    #pragma unroll
    for (int j=0;j<4;++j)
      #pragma unroll
      for (int r=0;r<4;++r)
        outp[(i*16+fq*4+r)*64 + j*16+fr] = acc[i][j][r];
}

// prefix combine: read f32 local sums, write bf16 prefix (consumed as bf16 anyway)
__global__ __launch_bounds__(256) void pair_combine(
    const float* __restrict__ pairbuf, const float* __restrict__ Dprod,
    unsigned short* __restrict__ pinitb){
  const int idx = blockIdx.x*256 + threadIdx.x;     // 262144
  const int de = idx & 4095, bh = idx >> 12;
  float acc = 0.f;
  for (int c=0;c<NCHUNK;++c){
    const size_t o = ((size_t)c*BH + bh)*4096 + de;
    pinitb[o] = f2bf(acc);
    acc = Dprod[c*BH + bh]*acc + pairbuf[o];
  }
}

// ---------- pair final: masked linear attention via MFMA ----------
__global__ __launch_bounds__(64) void pair_finalm(
    const unsigned short* __restrict__ proj, const float* __restrict__ pdo,
    const unsigned short* __restrict__ slocb, const float* __restrict__ Sarr,
    const float* __restrict__ sinit, const unsigned short* __restrict__ pinitb,
    unsigned short* __restrict__ lcqr){
  __shared__ __align__(16) unsigned short Bt[4096];
  __shared__ __align__(16) unsigned short Tb[4096];
  __shared__ __align__(16) float Dtl[64];
  __shared__ __align__(16) float cudl[64];
  const int c=blockIdx.x, bh=blockIdx.y, b=bh>>3, h=bh&7, l=threadIdx.x;
  const int t0 = c*CLEN;
  const int trow = t0 + l;
  float pd = pdo[(size_t)h*ROWS + b*S_+trow];
  float D = pd;
  #pragma unroll
  for (int m=1;m<64;m<<=1){ float o = __shfl_up(D, m); if (l>=m) D *= o; }
  Dtl[l]  = D;
  cudl[l] = (1.f - pd) / D;
  {
    const unsigned short* brow = proj + (size_t)(8+h)*PLANE + (size_t)(b*S_+trow)*64;
    #pragma unroll
    for (int e8=0;e8<8;++e8){
      ushort4 u0 = *(const ushort4*)(brow + e8*8);
      ushort4 u1 = *(const ushort4*)(brow + e8*8 + 4);
      unsigned short vs[8] = {u0.x,u0.y,u0.z,u0.w,u1.x,u1.y,u1.z,u1.w};
      #pragma unroll
      for (int q=0;q<8;++q) Bt[swz(e8*8+q, l)] = vs[q];
    }
  }
  __syncthreads();
  const int fr = l & 15, fq = l >> 4;
  const float* initp = sinit + ((size_t)c*BH + bh)*64;
  bf16x8 qf[4][2], pf[4][2];
  #pragma unroll
  for (int i=0;i<4;++i){
    const int tr = t0 + i*16 + fr;
    const bool first = (i==0 && fr==0);
    const size_t ptm = (size_t)bh*S_ + (first ? tr : tr-1);
    float sp = 0.f;
    if (!first) sp = Sarr[ptm];
    #pragma unroll
    for (int kh=0;kh<2;++kh){
      qf[i][kh] = *(const bf16x8*)(proj + (size_t)(16+h)*PLANE + (size_t)(b*S_ + tr)*64 + kh*32 + fq*8);
      bf16x8 sv = *(const bf16x8*)(slocb + ptm*64 + kh*32 + fq*8);
      float4 i0 = *(const float4*)(initp + kh*32 + fq*8);
      float4 i1 = *(const float4*)(initp + kh*32 + fq*8 + 4);
      float iv[8] = {i0.x,i0.y,i0.z,i0.w,i1.x,i1.y,i1.z,i1.w};
      bf16x8 pv;
      #pragma unroll
      for (int e=0;e<8;++e){
        float p = first ? iv[e] : (sp*iv[e] + (float)sv[e]);
        pv[e] = (__bf16)p;
      }
      pf[i][kh] = pv;
    }
  }
  floatx4 sacc[4][4];
  #pragma unroll
  for (int i=0;i<4;++i)
    #pragma unroll
    for (int j=0;j<4;++j) sacc[i][j] = (floatx4){0.f,0.f,0.f,0.f};
  #pragma unroll
  for (int kh=0;kh<2;++kh)
    #pragma unroll
    for (int i=0;i<4;++i)
      #pragma unroll
      for (int j=0;j<4;++j)
        sacc[i][j] = __builtin_amdgcn_mfma_f32_16x16x32_bf16(qf[i][kh], pf[j][kh], sacc[i][j], 0, 0, 0);
  float mycud[4];
  #pragma unroll
  for (int j=0;j<4;++j) mycud[j] = cudl[j*16+fr];
  #pragma unroll
  for (int i=0;i<4;++i){
    floatx4 dtv = *(const floatx4*)&Dtl[i*16+fq*4];
    #pragma unroll
    for (int j=0;j<4;++j){
      const int uu = j*16+fr;
      #pragma unroll
      for (int r=0;r<4;++r){
        const int tt = i*16+fq*4+r;
        float v = (uu<=tt) ? (sacc[i][j][r]*dtv[r])*mycud[j] : 0.f;
        Tb[swz(tt, uu)] = f2bf(v);
      }
    }
  }
  __syncthreads();
  floatx4 acc[4][4];
  #pragma unroll
  for (int i=0;i<4;++i)
    #pragma unroll
    for (int j=0;j<4;++j) acc[i][j] = (floatx4){0.f,0.f,0.f,0.f};
  #pragma unroll
  for (int kh=0;kh<2;++kh){
    bf16x8 af[4], bfr[4];
    #pragma unroll
    for (int i=0;i<4;++i) af[i]  = *(const bf16x8*)&Tb[swz(i*16+fr, kh*32+fq*8)];
    #pragma unroll
    for (int j=0;j<4;++j) bfr[j] = *(const bf16x8*)&Bt[swz(j*16+fr, kh*32+fq*8)];
    #pragma unroll
    for (int i=0;i<4;++i)
      #pragma unroll
      for (int j=0;j<4;++j)
        acc[i][j] = __builtin_amdgcn_mfma_f32_16x16x32_bf16(af[i], bfr[j], acc[i][j], 0, 0, 0);
  }
  {
    const unsigned short* ib = pinitb + ((size_t)c*BH + bh)*4096;
    #pragma unroll
    for (int kh=0;kh<2;++kh){
      bf16x8 qs[4], inf[4];
      #pragma unroll
      for (int i=0;i<4;++i){
        const float sc = Dtl[i*16+fr];
        #pragma unroll
        for (int e=0;e<8;++e) qs[i][e] = (__bf16)(sc * (float)qf[i][kh][e]);
      }
      #pragma unroll
      for (int j=0;j<4;++j)
        inf[j] = *(const bf16x8*)(ib + (j*16+fr)*64 + kh*32 + fq*8);
      #pragma unroll
      for (int i=0;i<4;++i)
        #pragma unroll
        for (int j=0;j<4;++j)
          acc[i][j] = __builtin_amdgcn_mfma_f32_16x16x32_bf16(qs[i], inf[j], acc[i][j], 0, 0, 0);
    }
  }
  __syncthreads();
  #pragma unroll
  for (int i=0;i<4;++i)
    #pragma unroll
    for (int j=0;j<4;++j)
      #pragma unroll
      for (int r=0;r<4;++r)
        Tb[swz(i*16+fq*4+r, j*16+fr)] = f2bf(acc[i][j][r]);
  __syncthreads();
  {
    const unsigned short* qrow = proj + (size_t)(24+h)*PLANE + (size_t)(b*S_+trow)*64;
    unsigned short* orow = lcqr + ((size_t)(b*S_+trow))*512 + h*64;
    #pragma unroll
    for (int e8=0;e8<8;++e8){
      bf16x8 lcv = *(const bf16x8*)&Tb[swz(l, e8*8)];
      ushort4 q0 = *(const ushort4*)(qrow + e8*8);
      ushort4 q1 = *(const ushort4*)(qrow + e8*8 + 4);
      unsigned short qv[8] = {q0.x,q0.y,q0.z,q0.w,q1.x,q1.y,q1.z,q1.w};
      ushort4 o0, o1;
      o0.x = f2bf((float)lcv[0]*bf2f(qv[0]));
      o0.y = f2bf((float)lcv[1]*bf2f(qv[1]));
      o0.z = f2bf((float)lcv[2]*bf2f(qv[2]));
      o0.w = f2bf((float)lcv[3]*bf2f(qv[3]));
      o1.x = f2bf((float)lcv[4]*bf2f(qv[4]));
      o1.y = f2bf((float)lcv[5]*bf2f(qv[5]));
      o1.z = f2bf((float)lcv[6]*bf2f(qv[6]));
      o1.w = f2bf((float)lcv[7]*bf2f(qv[7]));
      *(ushort4*)(orow + e8*8)     = o0;
      *(ushort4*)(orow + e8*8 + 4) = o1;
    }
  }
}

// ---------- launch ----------
extern "C" void kernel_launch(void* const* d_in, const int* in_sizes, int n_in,
                              void* d_out, int out_size, void* d_ws, size_t ws_size,
                              hipStream_t stream){
  (void)in_sizes; (void)n_in; (void)out_size; (void)ws_size;
  const float* x    = (const float*)d_in[0];
  const float* ng   = (const float*)d_in[1];
  const float* nb   = (const float*)d_in[2];
  const float* fng  = (const float*)d_in[3];
  const float* fnb  = (const float*)d_in[4];
  const float* Wa   = (const float*)d_in[5];
  const float* Wb   = (const float*)d_in[6];
  const float* Wql  = (const float*)d_in[7];
  const float* Wqr  = (const float*)d_in[8];
  const float* Wsd  = (const float*)d_in[9];
  const float* bsd  = (const float*)d_in[10];
  const float* Wpd  = (const float*)d_in[11];
  const float* bpd  = (const float*)d_in[12];
  const float* Wout = (const float*)d_in[13];
  const float* W1   = (const float*)d_in[14];
  const float* b1   = (const float*)d_in[15];
  const float* W2   = (const float*)d_in[16];
  const float* b2   = (const float*)d_in[17];
  float* out = (float*)d_out;
  char* ws = (char*)d_ws;

  size_t off = 0;
  auto alloc = [&](size_t bytes)->char*{ char* p = ws + off; off += (bytes + 255) & ~(size_t)255; return p; };
  char* RA = alloc((size_t)ROWS*DM_*2);      // nbf -> lcqr -> nr
  char* RB = alloc((size_t)ROWS*2048*2);     // proj (head-major planes) -> hbuf
  char* RD = alloc((size_t)NCHUNK*BH*4096*4);// pairbuf (f32 local sums)
  char* RE = alloc((size_t)BH*S_*64*4);      // front: slocb(bf16) -> rbufb(bf16); back: pinitb(bf16)
  float* sdo   = (float*)alloc((size_t)ROWS*8*4);
  float* pdo   = (float*)alloc((size_t)ROWS*8*4);
  float* Sarr  = (float*)alloc((size_t)BH*S_*4);
  float* sinit = (float*)alloc((size_t)NCHUNK*BH*64*4);
  float* sEnd  = (float*)alloc((size_t)NCHUNK*BH*64*4);
  float* dprod = (float*)alloc((size_t)NCHUNK*BH*4);
  unsigned short* wcat  = (unsigned short*)alloc((size_t)2048*512*2);
  unsigned short* woutb = (unsigned short*)alloc((size_t)512*512*2);
  unsigned short* w1b   = (unsigned short*)alloc((size_t)2048*512*2);
  unsigned short* w2b   = (unsigned short*)alloc((size_t)512*2048*2);

  unsigned short* nbf   = (unsigned short*)RA;
  unsigned short* lcqr  = (unsigned short*)RA;
  unsigned short* nr    = (unsigned short*)RA;
  unsigned short* proj  = (unsigned short*)RB;
  unsigned short* hbuf  = (unsigned short*)RB;
  float* pairb = (float*)RD;
  unsigned short* slocb  = (unsigned short*)RE;
  unsigned short* rbufb  = (unsigned short*)RE;
  unsigned short* pinitb = (unsigned short*)(RE + (size_t)BH*S_*64*2);

  cvt_weights<<<dim3(3328), dim3(256), 0, stream>>>(Wa,Wb,Wql,Wqr,Wout,W1,W2, wcat,woutb,w1b,w2b);
  ln_gates<<<dim3(ROWS/4), dim3(256), 0, stream>>>(x, ng, nb, Wsd, bsd, Wpd, bpd, nbf, sdo, pdo);
  gemm128<0><<<dim3(128,16), dim3(256), 0, stream>>>(nbf, wcat, nullptr, nullptr, nullptr, nullptr, proj, 2048, 512);
  state_local<<<dim3(NCHUNK,BH), dim3(64), 0, stream>>>(proj, sdo, slocb, Sarr, sEnd);
  state_combine<<<dim3(BH), dim3(64), 0, stream>>>(sEnd, Sarr, sinit);
  pair_localm<<<dim3(NCHUNK,BH), dim3(64), 0, stream>>>(proj, pdo, slocb, Sarr, sinit, pairb, dprod);
  pair_combine<<<dim3(1024), dim3(256), 0, stream>>>(pairb, dprod, pinitb);
  pair_finalm<<<dim3(NCHUNK,BH), dim3(64), 0, stream>>>(proj, pdo, slocb, Sarr, sinit, pinitb, lcqr);
  // Wout GEMM: 64x128 tile -> 1024 blocks (4/CU)
  gemm64<1><<<dim3(256,4), dim3(256), 0, stream>>>(lcqr, woutb, nullptr, x, nullptr, nullptr, rbufb, 512, 512);
  ln_plain<<<dim3(ROWS/4), dim3(256), 0, stream>>>(rbufb, fng, fnb, nr);
  gemm128<2><<<dim3(128,16), dim3(256), 0, stream>>>(nr, w1b, b1, nullptr, nullptr, nullptr, hbuf, 2048, 512);
  // FFN2: 64x128 tile -> 1024 blocks (4/CU), K=2048 deep loop
  gemm64<3><<<dim3(256,4), dim3(256), 0, stream>>>(hbuf, w2b, b2, nullptr, rbufb, out, nullptr, 512, 2048);
}

// Round 8
// 404.029 us; speedup vs baseline: 1.0320x; 1.0320x over previous
//
#include <hip/hip_runtime.h>
#include <cstdint>
#include <cstddef>

// Problem constants
#define B_    8
#define S_    2048
#define DM_   512
#define H_    8
#define SD_   64
#define HID_  2048
#define ROWS  (B_*S_)      // 16384
#define BH    (B_*H_)      // 64
#define NCHUNK 32
#define CLEN   64
#define EPS_  1e-5f
#define PLANE ((size_t)ROWS*64)   // one head-plane of proj: 16384*64 shorts

typedef __bf16 bf16x8 __attribute__((ext_vector_type(8)));
typedef float  floatx4 __attribute__((ext_vector_type(4)));

// proj layout is HEAD-MAJOR: proj[plane][row][64], plane = mat*8 + h,
// mat: 0=a(tanh), 1=b(tanh), 2=ql(tanh), 3=qr(tanh); row = b*S+t.
// Gate layout is HEAD-MAJOR too: sdo/pdo[h][ROWS] (coalesced t-runs for scan readers).
// pair kernels: 2 waves share one (c,bh) unit's 16KB LDS -> 20 waves/CU (was 10).

// ---------- small helpers ----------
static __device__ __forceinline__ float bf2f(unsigned short h){
  union { unsigned int u; float f; } v; v.u = ((unsigned int)h) << 16; return v.f;
}
static __device__ __forceinline__ unsigned short f2bf(float f){
  union { float f; unsigned int u; } v; v.f = f;
  unsigned int r = v.u + 0x7fffu + ((v.u >> 16) & 1u);
  return (unsigned short)(r >> 16);
}
static __device__ __forceinline__ float fast_tanh(float x){
  float ax = fabsf(x);
  float e  = __expf(2.f*ax);
  float t  = 1.f - 2.f/(e+1.f);
  return copysignf(t, x);
}
static __device__ __forceinline__ float sigmoidf_(float z){
  return 1.f/(1.f + expf(-z));
}
static __device__ __forceinline__ float gelu_exact(float x){
  return 0.5f*x*(1.f + erff(x*0.70710678118654752440f));
}
static __device__ __forceinline__ void gld_lds16(const unsigned short* g, unsigned short* lds){
  __builtin_amdgcn_global_load_lds(
      (const __attribute__((address_space(1))) void*)g,
      (__attribute__((address_space(3))) void*)lds,
      16, 0, 0);
}
// XOR swizzle for 64-half (128B) rows: 16B chunk kc of row r stored at chunk kc^(r&7)
static __device__ __forceinline__ int swz(int row, int col){
  return row*64 + (((col>>3) ^ (row&7))<<3) + (col&7);
}

// ---------- weight fp32 -> bf16 conversion ----------
__global__ __launch_bounds__(256) void cvt_weights(
    const float* __restrict__ wa, const float* __restrict__ wb,
    const float* __restrict__ wql, const float* __restrict__ wqr,
    const float* __restrict__ wout, const float* __restrict__ w1,
    const float* __restrict__ w2,
    unsigned short* __restrict__ wcat, unsigned short* __restrict__ woutb,
    unsigned short* __restrict__ w1b, unsigned short* __restrict__ w2b){
  int i = blockIdx.x*256 + threadIdx.x;   // float4 units, total 851968
  const float* s; unsigned short* d; int base;
  if      (i <  65536){ s=wa;   d=wcat;          base=i; }
  else if (i < 131072){ s=wb;   d=wcat+262144;   base=i-65536; }
  else if (i < 196608){ s=wql;  d=wcat+524288;   base=i-131072; }
  else if (i < 262144){ s=wqr;  d=wcat+786432;   base=i-196608; }
  else if (i < 327680){ s=wout; d=woutb;         base=i-262144; }
  else if (i < 589824){ s=w1;   d=w1b;           base=i-327680; }
  else                { s=w2;   d=w2b;           base=i-589824; }
  float4 v = ((const float4*)s)[base];
  ushort4 o; o.x=f2bf(v.x); o.y=f2bf(v.y); o.z=f2bf(v.z); o.w=f2bf(v.w);
  ((ushort4*)d)[base] = o;
}

// ---------- LN1 + gate heads (4 rows/block, 1 wave each) ----------
__global__ __launch_bounds__(256) void ln_gates(
    const float* __restrict__ x, const float* __restrict__ gam, const float* __restrict__ bet,
    const float* __restrict__ Wsd, const float* __restrict__ bsd,
    const float* __restrict__ Wpd, const float* __restrict__ bpd,
    unsigned short* __restrict__ nbf, float* __restrict__ sdo, float* __restrict__ pdo){
  const int row = blockIdx.x*4 + (threadIdx.x>>6), l = threadIdx.x & 63;
  const float* xr = x + (size_t)row*DM_;
  float4 v0 = ((const float4*)xr)[l*2];
  float4 v1 = ((const float4*)xr)[l*2+1];
  float v[8] = {v0.x,v0.y,v0.z,v0.w,v1.x,v1.y,v1.z,v1.w};
  float s = 0.f;
  #pragma unroll
  for (int i=0;i<8;++i) s += v[i];
  #pragma unroll
  for (int m=1;m<64;m<<=1) s += __shfl_xor(s, m);
  const float mean = s * (1.f/512.f);
  float q = 0.f;
  #pragma unroll
  for (int i=0;i<8;++i){ float d = v[i]-mean; q += d*d; }
  #pragma unroll
  for (int m=1;m<64;m<<=1) q += __shfl_xor(q, m);
  const float rstd = rsqrtf(q*(1.f/512.f) + EPS_);
  float4 g0 = ((const float4*)gam)[l*2], g1 = ((const float4*)gam)[l*2+1];
  float4 b0 = ((const float4*)bet)[l*2], b1 = ((const float4*)bet)[l*2+1];
  float gg[8] = {g0.x,g0.y,g0.z,g0.w,g1.x,g1.y,g1.z,g1.w};
  float bb[8] = {b0.x,b0.y,b0.z,b0.w,b1.x,b1.y,b1.z,b1.w};
  float n[8];
  #pragma unroll
  for (int i=0;i<8;++i) n[i] = (v[i]-mean)*rstd*gg[i] + bb[i];
  ushort4 o0, o1;
  o0.x=f2bf(n[0]); o0.y=f2bf(n[1]); o0.z=f2bf(n[2]); o0.w=f2bf(n[3]);
  o1.x=f2bf(n[4]); o1.y=f2bf(n[5]); o1.z=f2bf(n[6]); o1.w=f2bf(n[7]);
  ((ushort4*)(nbf + (size_t)row*DM_))[l*2]   = o0;
  ((ushort4*)(nbf + (size_t)row*DM_))[l*2+1] = o1;
  float acc[16];
  #pragma unroll
  for (int hh=0; hh<8; ++hh){
    const float4* ws = (const float4*)(Wsd + hh*DM_) + l*2;
    const float4* wp = (const float4*)(Wpd + hh*DM_) + l*2;
    float4 a0=ws[0], a1=ws[1], p0=wp[0], p1=wp[1];
    acc[hh]   = n[0]*a0.x+n[1]*a0.y+n[2]*a0.z+n[3]*a0.w+n[4]*a1.x+n[5]*a1.y+n[6]*a1.z+n[7]*a1.w;
    acc[8+hh] = n[0]*p0.x+n[1]*p0.y+n[2]*p0.z+n[3]*p0.w+n[4]*p1.x+n[5]*p1.y+n[6]*p1.z+n[7]*p1.w;
  }
  #pragma unroll
  for (int k=0;k<16;++k){
    float a = acc[k];
    #pragma unroll
    for (int m=1;m<64;m<<=1) a += __shfl_xor(a, m);
    acc[k] = a;
  }
  if (l==0){
    #pragma unroll
    for (int hh=0; hh<8; ++hh){
      sdo[(size_t)hh*ROWS + row] = sigmoidf_(acc[hh]   + bsd[hh]);
      pdo[(size_t)hh*ROWS + row] = sigmoidf_(acc[8+hh] + bpd[hh]);
    }
  }
}

// ---------- plain LN (FFN), bf16 input (4 rows/block) ----------
__global__ __launch_bounds__(256) void ln_plain(
    const unsigned short* __restrict__ xb, const float* __restrict__ gam, const float* __restrict__ bet,
    unsigned short* __restrict__ ob){
  const int row = blockIdx.x*4 + (threadIdx.x>>6), l = threadIdx.x & 63;
  const unsigned short* xr = xb + (size_t)row*DM_ + l*8;
  ushort4 u0 = *(const ushort4*)xr;
  ushort4 u1 = *(const ushort4*)(xr+4);
  float v[8] = {bf2f(u0.x),bf2f(u0.y),bf2f(u0.z),bf2f(u0.w),
                bf2f(u1.x),bf2f(u1.y),bf2f(u1.z),bf2f(u1.w)};
  float s = 0.f;
  #pragma unroll
  for (int i=0;i<8;++i) s += v[i];
  #pragma unroll
  for (int m=1;m<64;m<<=1) s += __shfl_xor(s, m);
  const float mean = s * (1.f/512.f);
  float q = 0.f;
  #pragma unroll
  for (int i=0;i<8;++i){ float d = v[i]-mean; q += d*d; }
  #pragma unroll
  for (int m=1;m<64;m<<=1) q += __shfl_xor(q, m);
  const float rstd = rsqrtf(q*(1.f/512.f) + EPS_);
  float4 g0 = ((const float4*)gam)[l*2], g1 = ((const float4*)gam)[l*2+1];
  float4 b0 = ((const float4*)bet)[l*2], b1 = ((const float4*)bet)[l*2+1];
  float gg[8] = {g0.x,g0.y,g0.z,g0.w,g1.x,g1.y,g1.z,g1.w};
  float bb[8] = {b0.x,b0.y,b0.z,b0.w,b1.x,b1.y,b1.z,b1.w};
  ushort4 o0, o1;
  o0.x=f2bf((v[0]-mean)*rstd*gg[0]+bb[0]); o0.y=f2bf((v[1]-mean)*rstd*gg[1]+bb[1]);
  o0.z=f2bf((v[2]-mean)*rstd*gg[2]+bb[2]); o0.w=f2bf((v[3]-mean)*rstd*gg[3]+bb[3]);
  o1.x=f2bf((v[4]-mean)*rstd*gg[4]+bb[4]); o1.y=f2bf((v[5]-mean)*rstd*gg[5]+bb[5]);
  o1.z=f2bf((v[6]-mean)*rstd*gg[6]+bb[6]); o1.w=f2bf((v[7]-mean)*rstd*gg[7]+bb[7]);
  ((ushort4*)(ob + (size_t)row*DM_))[l*2]   = o0;
  ((ushort4*)(ob + (size_t)row*DM_))[l*2+1] = o1;
}

// ---------- 128x128-tile GEMM, BK=64, single-buffered (measured-best structure) ----------
// Round-7 lesson: 64x128 tile (gemm64) regressed FFN2/Wout ~10us — 1.5x staging
// traffic per FLOP + 2x barriers. gemm128 for ALL GEMMs.
// MODE 0: tanh -> bf16 HEAD-MAJOR planes (proj); 1: +resid(f32) -> bf16;
// 2: +bias,gelu -> bf16; 3: +bias+resid(bf16) -> f32
template<int MODE>
__global__ __launch_bounds__(256) void gemm128(
    const unsigned short* __restrict__ A, const unsigned short* __restrict__ W,
    const float* __restrict__ bias, const float* __restrict__ residf,
    const unsigned short* __restrict__ residb,
    float* __restrict__ outf, unsigned short* __restrict__ outb,
    int N, int K){
  __shared__ __align__(16) unsigned short As[128*64];
  __shared__ __align__(16) unsigned short Ws[128*64];
  const int tid  = threadIdx.x;
  const int w    = tid >> 6;
  const int lane = tid & 63;
  const int mblk = blockIdx.x, nblk = blockIdx.y;
  const int mrow = (w >> 1) * 64;
  const int ncol = (w & 1) * 64;
  const int fr = lane & 15, fq = lane >> 4;

  int srow[4], scol[4];
  #pragma unroll
  for (int q=0;q<4;++q){
    const int p = q*256 + w*64 + lane;
    srow[q] = p >> 3;
    scol[q] = ((p & 7) ^ (srow[q] & 7)) * 8;
  }

  floatx4 acc[4][4];
  #pragma unroll
  for (int i=0;i<4;++i)
    #pragma unroll
    for (int j=0;j<4;++j)
      acc[i][j] = (floatx4){0.f,0.f,0.f,0.f};

  for (int k0=0; k0<K; k0+=64){
    #pragma unroll
    for (int q=0;q<4;++q){
      gld_lds16(A + (size_t)(mblk*128 + srow[q])*K + k0 + scol[q], As + (q*256 + w*64)*8);
      gld_lds16(W + (size_t)(nblk*128 + srow[q])*K + k0 + scol[q], Ws + (q*256 + w*64)*8);
    }
    __syncthreads();
    #pragma unroll
    for (int kh=0;kh<2;++kh){
      bf16x8 af[4], bf[4];
      #pragma unroll
      for (int i=0;i<4;++i) af[i] = *(const bf16x8*)&As[swz(mrow + i*16 + fr, kh*32 + fq*8)];
      #pragma unroll
      for (int j=0;j<4;++j) bf[j] = *(const bf16x8*)&Ws[swz(ncol + j*16 + fr, kh*32 + fq*8)];
      #pragma unroll
      for (int i=0;i<4;++i)
        #pragma unroll
        for (int j=0;j<4;++j)
          acc[i][j] = __builtin_amdgcn_mfma_f32_16x16x32_bf16(af[i], bf[j], acc[i][j], 0, 0, 0);
    }
    __syncthreads();
  }

  #pragma unroll
  for (int i=0;i<4;++i){
    const int grow_base = mblk*128 + mrow + i*16 + fq*4;
    #pragma unroll
    for (int j=0;j<4;++j){
      const int gcol = nblk*128 + ncol + j*16 + fr;
      float bias_v = 0.f;
      if (MODE==2 || MODE==3) bias_v = bias[gcol];
      #pragma unroll
      for (int r=0;r<4;++r){
        float v = acc[i][j][r];
        if (MODE==0){
          // head-major plane write: plane = gcol>>6, in-plane col = gcol&63
          const size_t o = (size_t)(gcol>>6)*PLANE + (size_t)(grow_base + r)*64 + (gcol & 63);
          outb[o] = f2bf(fast_tanh(v));
        } else {
          const size_t o = (size_t)(grow_base + r)*N + gcol;
          if      (MODE==1) outb[o] = f2bf(residf[o] + v);
          else if (MODE==2) outb[o] = f2bf(gelu_exact(v + bias_v));
          else              outf[o] = bf2f(residb[o]) + v + bias_v;
        }
      }
    }
  }
}

// ---------- state scan, chunk-local (LDS-staged; bf16 sloc + f32 chunk ends) ----------
__global__ __launch_bounds__(64) void state_local(
    const unsigned short* __restrict__ proj, const float* __restrict__ sdo,
    unsigned short* __restrict__ slocb, float* __restrict__ Sarr,
    float* __restrict__ sEnd){
  __shared__ __align__(16) unsigned short a_s[4096];
  __shared__ float sv_s[64];
  const int c = blockIdx.x, bh = blockIdx.y, b = bh>>3, h = bh&7, d = threadIdx.x;
  const int t0 = c*CLEN;
  // cooperative stage: 8 KB contiguous (64 t x 64 d) via float4 (16B) chunks
  const unsigned short* ap = proj + (size_t)h*PLANE + (size_t)(b*S_+t0)*64;
  #pragma unroll
  for (int q=0;q<8;++q)
    *(float4*)&a_s[(q*64 + d)*8] = *(const float4*)(ap + (size_t)(q*64 + d)*8);
  sv_s[d] = sdo[(size_t)h*ROWS + b*S_+t0+d];
  __syncthreads();
  float s = 0.f, S = 1.f;
  #pragma unroll 4
  for (int j=0;j<CLEN;++j){
    const int t = t0 + j;
    float a  = bf2f(a_s[j*64 + d]);
    float sv = sv_s[j];
    s = sv*s + (1.f-sv)*a;
    S *= sv;
    slocb[((size_t)bh*S_ + t)*64 + d] = f2bf(s);
    if (d==0) Sarr[bh*S_ + t] = S;
  }
  sEnd[((size_t)c*BH + bh)*64 + d] = s;
}

__global__ __launch_bounds__(64) void state_combine(
    const float* __restrict__ sEnd, const float* __restrict__ Sarr,
    float* __restrict__ sinit){
  const int bh = blockIdx.x, d = threadIdx.x;
  float acc = 0.f;
  for (int c=0;c<NCHUNK;++c){
    sinit[((size_t)c*BH + bh)*64 + d] = acc;
    const int te = c*CLEN + CLEN - 1;
    acc = Sarr[bh*S_ + te]*acc + sEnd[((size_t)c*BH + bh)*64 + d];
  }
}

// ---------- pair chunk-local sums via MFMA (2 waves share one unit's LDS) ----------
// wave w owns j in {2w, 2w+1} of the 4x4 fragment grid; staging e8-loop split.
// Same MFMA ops on same values in same order -> bitwise-identical output.
__global__ __launch_bounds__(128) void pair_localm(
    const unsigned short* __restrict__ proj, const float* __restrict__ pdo,
    const unsigned short* __restrict__ slocb, const float* __restrict__ Sarr,
    const float* __restrict__ sinit, float* __restrict__ pairbuf,
    float* __restrict__ Dprod){
  __shared__ __align__(16) unsigned short Bt[4096];
  __shared__ __align__(16) unsigned short Pt[4096];
  const int c=blockIdx.x, bh=blockIdx.y, b=bh>>3, h=bh&7;
  const int w = threadIdx.x>>6, l = threadIdx.x&63;
  const int t = c*CLEN + l;
  float pd = pdo[(size_t)h*ROWS + b*S_+t];
  float D = pd;                            // per-wave duplicate scan (identical values)
  #pragma unroll
  for (int m=1;m<64;m<<=1){ float o = __shfl_up(D, m); if (l>=m) D *= o; }
  const float Dend = __shfl(D, 63);
  const float cu = (Dend / D) * (1.f - pd);
  if (w==0 && l==63) Dprod[c*BH+bh] = Dend;
  {
    const unsigned short* brow = proj + (size_t)(8+h)*PLANE + (size_t)(b*S_+t)*64;
    const size_t ptm = (size_t)bh*S_ + (l==0 ? t : t-1);   // clamped (values unused when l==0)
    const unsigned short* srow = slocb + ptm*64;
    const float* initp = sinit + ((size_t)c*BH + bh)*64;
    float sp = 0.f;
    if (l>0) sp = Sarr[ptm];
    #pragma unroll
    for (int e8=w*4; e8<w*4+4; ++e8){
      ushort4 u0 = *(const ushort4*)(brow + e8*8);
      ushort4 u1 = *(const ushort4*)(brow + e8*8 + 4);
      unsigned short vs[8] = {u0.x,u0.y,u0.z,u0.w,u1.x,u1.y,u1.z,u1.w};
      ushort4 s0 = *(const ushort4*)(srow + e8*8);
      ushort4 s1 = *(const ushort4*)(srow + e8*8 + 4);
      unsigned short ss[8] = {s0.x,s0.y,s0.z,s0.w,s1.x,s1.y,s1.z,s1.w};
      float4 i0 = *(const float4*)(initp + e8*8);
      float4 i1 = *(const float4*)(initp + e8*8 + 4);
      float iv[8] = {i0.x,i0.y,i0.z,i0.w,i1.x,i1.y,i1.z,i1.w};
      #pragma unroll
      for (int q=0;q<8;++q){
        const int r = e8*8+q;
        float p = (l==0) ? iv[q] : (sp*iv[q] + bf2f(ss[q]));
        Bt[swz(r, l)] = f2bf(cu * bf2f(vs[q]));
        Pt[swz(r, l)] = f2bf(p);
      }
    }
  }
  __syncthreads();
  const int fr = l & 15, fq = l >> 4;
  floatx4 acc[4][2];
  #pragma unroll
  for (int i=0;i<4;++i)
    #pragma unroll
    for (int jj=0;jj<2;++jj) acc[i][jj] = (floatx4){0.f,0.f,0.f,0.f};
  #pragma unroll
  for (int kh=0;kh<2;++kh){
    bf16x8 af[4], bfr[2];
    #pragma unroll
    for (int i=0;i<4;++i)  af[i]  = *(const bf16x8*)&Bt[swz(i*16+fr, kh*32+fq*8)];
    #pragma unroll
    for (int jj=0;jj<2;++jj) bfr[jj] = *(const bf16x8*)&Pt[swz((w*2+jj)*16+fr, kh*32+fq*8)];
    #pragma unroll
    for (int i=0;i<4;++i)
      #pragma unroll
      for (int jj=0;jj<2;++jj)
        acc[i][jj] = __builtin_amdgcn_mfma_f32_16x16x32_bf16(af[i], bfr[jj], acc[i][jj], 0, 0, 0);
  }
  float* outp = pairbuf + ((size_t)c*BH + bh)*4096;
  #pragma unroll
  for (int i=0;i<4;++i)
    #pragma unroll
    for (int jj=0;jj<2;++jj)
      #pragma unroll
      for (int r=0;r<4;++r)
        outp[(i*16+fq*4+r)*64 + (w*2+jj)*16+fr] = acc[i][jj][r];
}

// prefix combine: read f32 local sums, write bf16 prefix (consumed as bf16 anyway)
__global__ __launch_bounds__(256) void pair_combine(
    const float* __restrict__ pairbuf, const float* __restrict__ Dprod,
    unsigned short* __restrict__ pinitb){
  const int idx = blockIdx.x*256 + threadIdx.x;     // 262144
  const int de = idx & 4095, bh = idx >> 12;
  float acc = 0.f;
  for (int c=0;c<NCHUNK;++c){
    const size_t o = ((size_t)c*BH + bh)*4096 + de;
    pinitb[o] = f2bf(acc);
    acc = Dprod[c*BH + bh]*acc + pairbuf[o];
  }
}

// ---------- pair final: masked linear attention via MFMA (2 waves / unit) ----------
__global__ __launch_bounds__(128) void pair_finalm(
    const unsigned short* __restrict__ proj, const float* __restrict__ pdo,
    const unsigned short* __restrict__ slocb, const float* __restrict__ Sarr,
    const float* __restrict__ sinit, const unsigned short* __restrict__ pinitb,
    unsigned short* __restrict__ lcqr){
  __shared__ __align__(16) unsigned short Bt[4096];
  __shared__ __align__(16) unsigned short Tb[4096];
  __shared__ __align__(16) float Dtl[64];
  __shared__ __align__(16) float cudl[64];
  const int c=blockIdx.x, bh=blockIdx.y, b=bh>>3, h=bh&7;
  const int w=threadIdx.x>>6, l=threadIdx.x&63;
  const int t0 = c*CLEN;
  const int trow = t0 + l;
  float pd = pdo[(size_t)h*ROWS + b*S_+trow];
  float D = pd;                            // per-wave duplicate scan
  #pragma unroll
  for (int m=1;m<64;m<<=1){ float o = __shfl_up(D, m); if (l>=m) D *= o; }
  if (w==0){ Dtl[l] = D; cudl[l] = (1.f - pd) / D; }
  {
    const unsigned short* brow = proj + (size_t)(8+h)*PLANE + (size_t)(b*S_+trow)*64;
    #pragma unroll
    for (int e8=w*4; e8<w*4+4; ++e8){
      ushort4 u0 = *(const ushort4*)(brow + e8*8);
      ushort4 u1 = *(const ushort4*)(brow + e8*8 + 4);
      unsigned short vs[8] = {u0.x,u0.y,u0.z,u0.w,u1.x,u1.y,u1.z,u1.w};
      #pragma unroll
      for (int q=0;q<8;++q) Bt[swz(e8*8+q, l)] = vs[q];
    }
  }
  __syncthreads();
  const int fr = l & 15, fq = l >> 4;
  const float* initp = sinit + ((size_t)c*BH + bh)*64;
  bf16x8 qf[4][2], pf[2][2];
  #pragma unroll
  for (int i=0;i<4;++i)
    #pragma unroll
    for (int kh=0;kh<2;++kh)
      qf[i][kh] = *(const bf16x8*)(proj + (size_t)(16+h)*PLANE + (size_t)(b*S_ + t0 + i*16 + fr)*64 + kh*32 + fq*8);
  #pragma unroll
  for (int jw=0;jw<2;++jw){
    const int jx = w*2+jw;
    const int tr = t0 + jx*16 + fr;
    const bool first = (jx==0 && fr==0);
    const size_t ptm = (size_t)bh*S_ + (first ? tr : tr-1);
    float sp = 0.f;
    if (!first) sp = Sarr[ptm];
    #pragma unroll
    for (int kh=0;kh<2;++kh){
      bf16x8 sv = *(const bf16x8*)(slocb + ptm*64 + kh*32 + fq*8);
      float4 i0 = *(const float4*)(initp + kh*32 + fq*8);
      float4 i1 = *(const float4*)(initp + kh*32 + fq*8 + 4);
      float iv[8] = {i0.x,i0.y,i0.z,i0.w,i1.x,i1.y,i1.z,i1.w};
      bf16x8 pv;
      #pragma unroll
      for (int e=0;e<8;++e){
        float p = first ? iv[e] : (sp*iv[e] + (float)sv[e]);
        pv[e] = (__bf16)p;
      }
      pf[jw][kh] = pv;
    }
  }
  floatx4 sacc[4][2];
  #pragma unroll
  for (int i=0;i<4;++i)
    #pragma unroll
    for (int jw=0;jw<2;++jw) sacc[i][jw] = (floatx4){0.f,0.f,0.f,0.f};
  #pragma unroll
  for (int kh=0;kh<2;++kh)
    #pragma unroll
    for (int i=0;i<4;++i)
      #pragma unroll
      for (int jw=0;jw<2;++jw)
        sacc[i][jw] = __builtin_amdgcn_mfma_f32_16x16x32_bf16(qf[i][kh], pf[jw][kh], sacc[i][jw], 0, 0, 0);
  float mycud[2];
  #pragma unroll
  for (int jw=0;jw<2;++jw) mycud[jw] = cudl[(w*2+jw)*16+fr];
  #pragma unroll
  for (int i=0;i<4;++i){
    floatx4 dtv = *(const floatx4*)&Dtl[i*16+fq*4];
    #pragma unroll
    for (int jw=0;jw<2;++jw){
      const int uu = (w*2+jw)*16+fr;
      #pragma unroll
      for (int r=0;r<4;++r){
        const int tt = i*16+fq*4+r;
        float v = (uu<=tt) ? (sacc[i][jw][r]*dtv[r])*mycud[jw] : 0.f;
        Tb[swz(tt, uu)] = f2bf(v);
      }
    }
  }
  __syncthreads();
  floatx4 acc[4][2];
  #pragma unroll
  for (int i=0;i<4;++i)
    #pragma unroll
    for (int jw=0;jw<2;++jw) acc[i][jw] = (floatx4){0.f,0.f,0.f,0.f};
  #pragma unroll
  for (int kh=0;kh<2;++kh){
    bf16x8 af[4], bfr[2];
    #pragma unroll
    for (int i=0;i<4;++i)  af[i]  = *(const bf16x8*)&Tb[swz(i*16+fr, kh*32+fq*8)];
    #pragma unroll
    for (int jw=0;jw<2;++jw) bfr[jw] = *(const bf16x8*)&Bt[swz((w*2+jw)*16+fr, kh*32+fq*8)];
    #pragma unroll
    for (int i=0;i<4;++i)
      #pragma unroll
      for (int jw=0;jw<2;++jw)
        acc[i][jw] = __builtin_amdgcn_mfma_f32_16x16x32_bf16(af[i], bfr[jw], acc[i][jw], 0, 0, 0);
  }
  {
    const unsigned short* ib = pinitb + ((size_t)c*BH + bh)*4096;
    #pragma unroll
    for (int kh=0;kh<2;++kh){
      bf16x8 qs[4], inf[2];
      #pragma unroll
      for (int i=0;i<4;++i){
        const float sc = Dtl[i*16+fr];
        #pragma unroll
        for (int e=0;e<8;++e) qs[i][e] = (__bf16)(sc * (float)qf[i][kh][e]);
      }
      #pragma unroll
      for (int jw=0;jw<2;++jw)
        inf[jw] = *(const bf16x8*)(ib + ((w*2+jw)*16+fr)*64 + kh*32 + fq*8);
      #pragma unroll
      for (int i=0;i<4;++i)
        #pragma unroll
        for (int jw=0;jw<2;++jw)
          acc[i][jw] = __builtin_amdgcn_mfma_f32_16x16x32_bf16(qs[i], inf[jw], acc[i][jw], 0, 0, 0);
    }
  }
  __syncthreads();
  #pragma unroll
  for (int i=0;i<4;++i)
    #pragma unroll
    for (int jw=0;jw<2;++jw)
      #pragma unroll
      for (int r=0;r<4;++r)
        Tb[swz(i*16+fq*4+r, (w*2+jw)*16+fr)] = f2bf(acc[i][jw][r]);
  __syncthreads();
  {
    const unsigned short* qrow = proj + (size_t)(24+h)*PLANE + (size_t)(b*S_+trow)*64;
    unsigned short* orow = lcqr + ((size_t)(b*S_+trow))*512 + h*64;
    #pragma unroll
    for (int e8=w*4; e8<w*4+4; ++e8){
      bf16x8 lcv = *(const bf16x8*)&Tb[swz(l, e8*8)];
      ushort4 q0 = *(const ushort4*)(qrow + e8*8);
      ushort4 q1 = *(const ushort4*)(qrow + e8*8 + 4);
      unsigned short qv[8] = {q0.x,q0.y,q0.z,q0.w,q1.x,q1.y,q1.z,q1.w};
      ushort4 o0, o1;
      o0.x = f2bf((float)lcv[0]*bf2f(qv[0]));
      o0.y = f2bf((float)lcv[1]*bf2f(qv[1]));
      o0.z = f2bf((float)lcv[2]*bf2f(qv[2]));
      o0.w = f2bf((float)lcv[3]*bf2f(qv[3]));
      o1.x = f2bf((float)lcv[4]*bf2f(qv[4]));
      o1.y = f2bf((float)lcv[5]*bf2f(qv[5]));
      o1.z = f2bf((float)lcv[6]*bf2f(qv[6]));
      o1.w = f2bf((float)lcv[7]*bf2f(qv[7]));
      *(ushort4*)(orow + e8*8)     = o0;
      *(ushort4*)(orow + e8*8 + 4) = o1;
    }
  }
}

// ---------- launch ----------
extern "C" void kernel_launch(void* const* d_in, const int* in_sizes, int n_in,
                              void* d_out, int out_size, void* d_ws, size_t ws_size,
                              hipStream_t stream){
  (void)in_sizes; (void)n_in; (void)out_size; (void)ws_size;
  const float* x    = (const float*)d_in[0];
  const float* ng   = (const float*)d_in[1];
  const float* nb   = (const float*)d_in[2];
  const float* fng  = (const float*)d_in[3];
  const float* fnb  = (const float*)d_in[4];
  const float* Wa   = (const float*)d_in[5];
  const float* Wb   = (const float*)d_in[6];
  const float* Wql  = (const float*)d_in[7];
  const float* Wqr  = (const float*)d_in[8];
  const float* Wsd  = (const float*)d_in[9];
  const float* bsd  = (const float*)d_in[10];
  const float* Wpd  = (const float*)d_in[11];
  const float* bpd  = (const float*)d_in[12];
  const float* Wout = (const float*)d_in[13];
  const float* W1   = (const float*)d_in[14];
  const float* b1   = (const float*)d_in[15];
  const float* W2   = (const float*)d_in[16];
  const float* b2   = (const float*)d_in[17];
  float* out = (float*)d_out;
  char* ws = (char*)d_ws;

  size_t off = 0;
  auto alloc = [&](size_t bytes)->char*{ char* p = ws + off; off += (bytes + 255) & ~(size_t)255; return p; };
  char* RA = alloc((size_t)ROWS*DM_*2);      // nbf -> lcqr -> nr
  char* RB = alloc((size_t)ROWS*2048*2);     // proj (head-major planes) -> hbuf
  char* RD = alloc((size_t)NCHUNK*BH*4096*4);// pairbuf (f32 local sums)
  char* RE = alloc((size_t)BH*S_*64*4);      // front: slocb(bf16) -> rbufb(bf16); back: pinitb(bf16)
  float* sdo   = (float*)alloc((size_t)ROWS*8*4);
  float* pdo   = (float*)alloc((size_t)ROWS*8*4);
  float* Sarr  = (float*)alloc((size_t)BH*S_*4);
  float* sinit = (float*)alloc((size_t)NCHUNK*BH*64*4);
  float* sEnd  = (float*)alloc((size_t)NCHUNK*BH*64*4);
  float* dprod = (float*)alloc((size_t)NCHUNK*BH*4);
  unsigned short* wcat  = (unsigned short*)alloc((size_t)2048*512*2);
  unsigned short* woutb = (unsigned short*)alloc((size_t)512*512*2);
  unsigned short* w1b   = (unsigned short*)alloc((size_t)2048*512*2);
  unsigned short* w2b   = (unsigned short*)alloc((size_t)512*2048*2);

  unsigned short* nbf   = (unsigned short*)RA;
  unsigned short* lcqr  = (unsigned short*)RA;
  unsigned short* nr    = (unsigned short*)RA;
  unsigned short* proj  = (unsigned short*)RB;
  unsigned short* hbuf  = (unsigned short*)RB;
  float* pairb = (float*)RD;
  unsigned short* slocb  = (unsigned short*)RE;
  unsigned short* rbufb  = (unsigned short*)RE;
  unsigned short* pinitb = (unsigned short*)(RE + (size_t)BH*S_*64*2);

  cvt_weights<<<dim3(3328), dim3(256), 0, stream>>>(Wa,Wb,Wql,Wqr,Wout,W1,W2, wcat,woutb,w1b,w2b);
  ln_gates<<<dim3(ROWS/4), dim3(256), 0, stream>>>(x, ng, nb, Wsd, bsd, Wpd, bpd, nbf, sdo, pdo);
  gemm128<0><<<dim3(128,16), dim3(256), 0, stream>>>(nbf, wcat, nullptr, nullptr, nullptr, nullptr, proj, 2048, 512);
  state_local<<<dim3(NCHUNK,BH), dim3(64), 0, stream>>>(proj, sdo, slocb, Sarr, sEnd);
  state_combine<<<dim3(BH), dim3(64), 0, stream>>>(sEnd, Sarr, sinit);
  pair_localm<<<dim3(NCHUNK,BH), dim3(128), 0, stream>>>(proj, pdo, slocb, Sarr, sinit, pairb, dprod);
  pair_combine<<<dim3(1024), dim3(256), 0, stream>>>(pairb, dprod, pinitb);
  pair_finalm<<<dim3(NCHUNK,BH), dim3(128), 0, stream>>>(proj, pdo, slocb, Sarr, sinit, pinitb, lcqr);
  gemm128<1><<<dim3(128,4), dim3(256), 0, stream>>>(lcqr, woutb, nullptr, x, nullptr, nullptr, rbufb, 512, 512);
  ln_plain<<<dim3(ROWS/4), dim3(256), 0, stream>>>(rbufb, fng, fnb, nr);
  gemm128<2><<<dim3(128,16), dim3(256), 0, stream>>>(nr, w1b, b1, nullptr, nullptr, nullptr, hbuf, 2048, 512);
  gemm128<3><<<dim3(128,4), dim3(256), 0, stream>>>(hbuf, w2b, b2, nullptr, rbufb, out, nullptr, 512, 2048);
}

// Round 10
// 403.707 us; speedup vs baseline: 1.0328x; 1.0008x over previous
//
#include <hip/hip_runtime.h>
#include <cstdint>
#include <cstddef>

// Problem constants
#define B_    8
#define S_    2048
#define DM_   512
#define H_    8
#define SD_   64
#define HID_  2048
#define ROWS  (B_*S_)      // 16384
#define BH    (B_*H_)      // 64
#define NCHUNK 32
#define CLEN   64
#define EPS_  1e-5f
#define PLANE ((size_t)ROWS*64)   // one head-plane of proj: 16384*64 shorts

typedef __bf16 bf16x8 __attribute__((ext_vector_type(8)));
typedef float  floatx4 __attribute__((ext_vector_type(4)));

// proj layout is HEAD-MAJOR: proj[plane][row][64], plane = mat*8 + h.
// Gate layout HEAD-MAJOR: sdo/pdo[h][ROWS].
// pair kernels: 2 waves share one (c,bh) unit's 16KB LDS.
// FFN2: 256x128-tile 4-phase pipeline, nt=32, triple-buffered LDS, counted vmcnt.

// ---------- small helpers ----------
static __device__ __forceinline__ float bf2f(unsigned short h){
  union { unsigned int u; float f; } v; v.u = ((unsigned int)h) << 16; return v.f;
}
static __device__ __forceinline__ unsigned short f2bf(float f){
  union { float f; unsigned int u; } v; v.f = f;
  unsigned int r = v.u + 0x7fffu + ((v.u >> 16) & 1u);
  return (unsigned short)(r >> 16);
}
static __device__ __forceinline__ float fast_tanh(float x){
  float ax = fabsf(x);
  float e  = __expf(2.f*ax);
  float t  = 1.f - 2.f/(e+1.f);
  return copysignf(t, x);
}
static __device__ __forceinline__ float sigmoidf_(float z){
  return 1.f/(1.f + expf(-z));
}
static __device__ __forceinline__ float gelu_exact(float x){
  return 0.5f*x*(1.f + erff(x*0.70710678118654752440f));
}
static __device__ __forceinline__ void gld_lds16(const unsigned short* g, unsigned short* lds){
  __builtin_amdgcn_global_load_lds(
      (const __attribute__((address_space(1))) void*)g,
      (__attribute__((address_space(3))) void*)lds,
      16, 0, 0);
}
// XOR swizzle for 64-half (128B) rows: 16B chunk kc of row r stored at chunk kc^(r&7)
static __device__ __forceinline__ int swz(int row, int col){
  return row*64 + (((col>>3) ^ (row&7))<<3) + (col&7);
}

// ---------- weight fp32 -> bf16 conversion ----------
__global__ __launch_bounds__(256) void cvt_weights(
    const float* __restrict__ wa, const float* __restrict__ wb,
    const float* __restrict__ wql, const float* __restrict__ wqr,
    const float* __restrict__ wout, const float* __restrict__ w1,
    const float* __restrict__ w2,
    unsigned short* __restrict__ wcat, unsigned short* __restrict__ woutb,
    unsigned short* __restrict__ w1b, unsigned short* __restrict__ w2b){
  int i = blockIdx.x*256 + threadIdx.x;   // float4 units, total 851968
  const float* s; unsigned short* d; int base;
  if      (i <  65536){ s=wa;   d=wcat;          base=i; }
  else if (i < 131072){ s=wb;   d=wcat+262144;   base=i-65536; }
  else if (i < 196608){ s=wql;  d=wcat+524288;   base=i-131072; }
  else if (i < 262144){ s=wqr;  d=wcat+786432;   base=i-196608; }
  else if (i < 327680){ s=wout; d=woutb;         base=i-262144; }
  else if (i < 589824){ s=w1;   d=w1b;           base=i-327680; }
  else                { s=w2;   d=w2b;           base=i-589824; }
  float4 v = ((const float4*)s)[base];
  ushort4 o; o.x=f2bf(v.x); o.y=f2bf(v.y); o.z=f2bf(v.z); o.w=f2bf(v.w);
  ((ushort4*)d)[base] = o;
}

// ---------- LN1 + gate heads (4 rows/block, 1 wave each) ----------
__global__ __launch_bounds__(256) void ln_gates(
    const float* __restrict__ x, const float* __restrict__ gam, const float* __restrict__ bet,
    const float* __restrict__ Wsd, const float* __restrict__ bsd,
    const float* __restrict__ Wpd, const float* __restrict__ bpd,
    unsigned short* __restrict__ nbf, float* __restrict__ sdo, float* __restrict__ pdo){
  const int row = blockIdx.x*4 + (threadIdx.x>>6), l = threadIdx.x & 63;
  const float* xr = x + (size_t)row*DM_;
  float4 v0 = ((const float4*)xr)[l*2];
  float4 v1 = ((const float4*)xr)[l*2+1];
  float v[8] = {v0.x,v0.y,v0.z,v0.w,v1.x,v1.y,v1.z,v1.w};
  float s = 0.f;
  #pragma unroll
  for (int i=0;i<8;++i) s += v[i];
  #pragma unroll
  for (int m=1;m<64;m<<=1) s += __shfl_xor(s, m);
  const float mean = s * (1.f/512.f);
  float q = 0.f;
  #pragma unroll
  for (int i=0;i<8;++i){ float d = v[i]-mean; q += d*d; }
  #pragma unroll
  for (int m=1;m<64;m<<=1) q += __shfl_xor(q, m);
  const float rstd = rsqrtf(q*(1.f/512.f) + EPS_);
  float4 g0 = ((const float4*)gam)[l*2], g1 = ((const float4*)gam)[l*2+1];
  float4 b0 = ((const float4*)bet)[l*2], b1 = ((const float4*)bet)[l*2+1];
  float gg[8] = {g0.x,g0.y,g0.z,g0.w,g1.x,g1.y,g1.z,g1.w};
  float bb[8] = {b0.x,b0.y,b0.z,b0.w,b1.x,b1.y,b1.z,b1.w};
  float n[8];
  #pragma unroll
  for (int i=0;i<8;++i) n[i] = (v[i]-mean)*rstd*gg[i] + bb[i];
  ushort4 o0, o1;
  o0.x=f2bf(n[0]); o0.y=f2bf(n[1]); o0.z=f2bf(n[2]); o0.w=f2bf(n[3]);
  o1.x=f2bf(n[4]); o1.y=f2bf(n[5]); o1.z=f2bf(n[6]); o1.w=f2bf(n[7]);
  ((ushort4*)(nbf + (size_t)row*DM_))[l*2]   = o0;
  ((ushort4*)(nbf + (size_t)row*DM_))[l*2+1] = o1;
  float acc[16];
  #pragma unroll
  for (int hh=0; hh<8; ++hh){
    const float4* ws = (const float4*)(Wsd + hh*DM_) + l*2;
    const float4* wp = (const float4*)(Wpd + hh*DM_) + l*2;
    float4 a0=ws[0], a1=ws[1], p0=wp[0], p1=wp[1];
    acc[hh]   = n[0]*a0.x+n[1]*a0.y+n[2]*a0.z+n[3]*a0.w+n[4]*a1.x+n[5]*a1.y+n[6]*a1.z+n[7]*a1.w;
    acc[8+hh] = n[0]*p0.x+n[1]*p0.y+n[2]*p0.z+n[3]*p0.w+n[4]*p1.x+n[5]*p1.y+n[6]*p1.z+n[7]*p1.w;
  }
  #pragma unroll
  for (int k=0;k<16;++k){
    float a = acc[k];
    #pragma unroll
    for (int m=1;m<64;m<<=1) a += __shfl_xor(a, m);
    acc[k] = a;
  }
  if (l==0){
    #pragma unroll
    for (int hh=0; hh<8; ++hh){
      sdo[(size_t)hh*ROWS + row] = sigmoidf_(acc[hh]   + bsd[hh]);
      pdo[(size_t)hh*ROWS + row] = sigmoidf_(acc[8+hh] + bpd[hh]);
    }
  }
}

// ---------- plain LN (FFN), bf16 input (4 rows/block) ----------
__global__ __launch_bounds__(256) void ln_plain(
    const unsigned short* __restrict__ xb, const float* __restrict__ gam, const float* __restrict__ bet,
    unsigned short* __restrict__ ob){
  const int row = blockIdx.x*4 + (threadIdx.x>>6), l = threadIdx.x & 63;
  const unsigned short* xr = xb + (size_t)row*DM_ + l*8;
  ushort4 u0 = *(const ushort4*)xr;
  ushort4 u1 = *(const ushort4*)(xr+4);
  float v[8] = {bf2f(u0.x),bf2f(u0.y),bf2f(u0.z),bf2f(u0.w),
                bf2f(u1.x),bf2f(u1.y),bf2f(u1.z),bf2f(u1.w)};
  float s = 0.f;
  #pragma unroll
  for (int i=0;i<8;++i) s += v[i];
  #pragma unroll
  for (int m=1;m<64;m<<=1) s += __shfl_xor(s, m);
  const float mean = s * (1.f/512.f);
  float q = 0.f;
  #pragma unroll
  for (int i=0;i<8;++i){ float d = v[i]-mean; q += d*d; }
  #pragma unroll
  for (int m=1;m<64;m<<=1) q += __shfl_xor(q, m);
  const float rstd = rsqrtf(q*(1.f/512.f) + EPS_);
  float4 g0 = ((const float4*)gam)[l*2], g1 = ((const float4*)gam)[l*2+1];
  float4 b0 = ((const float4*)bet)[l*2], b1 = ((const float4*)bet)[l*2+1];
  float gg[8] = {g0.x,g0.y,g0.z,g0.w,g1.x,g1.y,g1.z,g1.w};
  float bb[8] = {b0.x,b0.y,b0.z,b0.w,b1.x,b1.y,b1.z,b1.w};
  ushort4 o0, o1;
  o0.x=f2bf((v[0]-mean)*rstd*gg[0]+bb[0]); o0.y=f2bf((v[1]-mean)*rstd*gg[1]+bb[1]);
  o0.z=f2bf((v[2]-mean)*rstd*gg[2]+bb[2]); o0.w=f2bf((v[3]-mean)*rstd*gg[3]+bb[3]);
  o1.x=f2bf((v[4]-mean)*rstd*gg[4]+bb[4]); o1.y=f2bf((v[5]-mean)*rstd*gg[5]+bb[5]);
  o1.z=f2bf((v[6]-mean)*rstd*gg[6]+bb[6]); o1.w=f2bf((v[7]-mean)*rstd*gg[7]+bb[7]);
  ((ushort4*)(ob + (size_t)row*DM_))[l*2]   = o0;
  ((ushort4*)(ob + (size_t)row*DM_))[l*2+1] = o1;
}

// ---------- 128x128-tile GEMM, BK=64, single-buffered ----------
// MODE 0: tanh -> bf16 HEAD-MAJOR planes (proj); 1: +resid(f32) -> bf16;
// 2: +bias,gelu -> bf16; 3: +bias+resid(bf16) -> f32
template<int MODE>
__global__ __launch_bounds__(256) void gemm128(
    const unsigned short* __restrict__ A, const unsigned short* __restrict__ W,
    const float* __restrict__ bias, const float* __restrict__ residf,
    const unsigned short* __restrict__ residb,
    float* __restrict__ outf, unsigned short* __restrict__ outb,
    int N, int K){
  __shared__ __align__(16) unsigned short As[128*64];
  __shared__ __align__(16) unsigned short Ws[128*64];
  const int tid  = threadIdx.x;
  const int w    = tid >> 6;
  const int lane = tid & 63;
  const int mblk = blockIdx.x, nblk = blockIdx.y;
  const int mrow = (w >> 1) * 64;
  const int ncol = (w & 1) * 64;
  const int fr = lane & 15, fq = lane >> 4;

  int srow[4], scol[4];
  #pragma unroll
  for (int q=0;q<4;++q){
    const int p = q*256 + w*64 + lane;
    srow[q] = p >> 3;
    scol[q] = ((p & 7) ^ (srow[q] & 7)) * 8;
  }

  floatx4 acc[4][4];
  #pragma unroll
  for (int i=0;i<4;++i)
    #pragma unroll
    for (int j=0;j<4;++j)
      acc[i][j] = (floatx4){0.f,0.f,0.f,0.f};

  for (int k0=0; k0<K; k0+=64){
    #pragma unroll
    for (int q=0;q<4;++q){
      gld_lds16(A + (size_t)(mblk*128 + srow[q])*K + k0 + scol[q], As + (q*256 + w*64)*8);
      gld_lds16(W + (size_t)(nblk*128 + srow[q])*K + k0 + scol[q], Ws + (q*256 + w*64)*8);
    }
    __syncthreads();
    #pragma unroll
    for (int kh=0;kh<2;++kh){
      bf16x8 af[4], bf[4];
      #pragma unroll
      for (int i=0;i<4;++i) af[i] = *(const bf16x8*)&As[swz(mrow + i*16 + fr, kh*32 + fq*8)];
      #pragma unroll
      for (int j=0;j<4;++j) bf[j] = *(const bf16x8*)&Ws[swz(ncol + j*16 + fr, kh*32 + fq*8)];
      #pragma unroll
      for (int i=0;i<4;++i)
        #pragma unroll
        for (int j=0;j<4;++j)
          acc[i][j] = __builtin_amdgcn_mfma_f32_16x16x32_bf16(af[i], bf[j], acc[i][j], 0, 0, 0);
    }
    __syncthreads();
  }

  #pragma unroll
  for (int i=0;i<4;++i){
    const int grow_base = mblk*128 + mrow + i*16 + fq*4;
    #pragma unroll
    for (int j=0;j<4;++j){
      const int gcol = nblk*128 + ncol + j*16 + fr;
      float bias_v = 0.f;
      if (MODE==2 || MODE==3) bias_v = bias[gcol];
      #pragma unroll
      for (int r=0;r<4;++r){
        float v = acc[i][j][r];
        if (MODE==0){
          const size_t o = (size_t)(gcol>>6)*PLANE + (size_t)(grow_base + r)*64 + (gcol & 63);
          outb[o] = f2bf(fast_tanh(v));
        } else {
          const size_t o = (size_t)(grow_base + r)*N + gcol;
          if      (MODE==1) outb[o] = f2bf(residf[o] + v);
          else if (MODE==2) outb[o] = f2bf(gelu_exact(v + bias_v));
          else              outf[o] = bf2f(residb[o]) + v + bias_v;
        }
      }
    }
  }
}

// ---------- FFN2 GEMM: 256x128-tile, 4-phase, triple-buffered, counted vmcnt ----------
// M=16384,N=512,K=2048 -> grid (64,4)=256 blocks (1/CU), nt=32 (deep pipeline).
// 8 waves (2M x 4N), per-wave 128x32 output. LDS 3 x (A 32K + W 16K) = 144 KB.
// Tile t+2's 6 global_load_lds are issued 2-per-phase during tile t (buffer (t+2)%3
// was fully consumed at tile t-1's P3 barrier). vmcnt(6) at tile entry keeps tile
// t+1's loads in flight; never drains to 0 except the last tile.
// Accumulation per element: tiles ascending, kh0 then kh1 — bitwise-identical to gemm128<3>.
__global__ __launch_bounds__(512, 2) void gemm_ffn2(
    const unsigned short* __restrict__ A, const unsigned short* __restrict__ W,
    const float* __restrict__ bias, const unsigned short* __restrict__ residb,
    float* __restrict__ outf, int N, int K){
  __shared__ __align__(16) unsigned short lds[73728];   // 144 KB
  const int tid  = threadIdx.x;
  const int w    = tid >> 6;          // wave 0..7
  const int lane = tid & 63;
  const int mrow = (w >> 2) * 128;    // wave M-base
  const int ncol = (w & 3) * 32;      // wave N-base
  const int fr = lane & 15, fq = lane >> 4;
  const int mblk = blockIdx.x, nblk = blockIdx.y;
  const int nt = K >> 6;              // 32

  int srA[4], scA[4];                 // A: 256x64 = 2048 chunks / 512 thr = 4 each
  #pragma unroll
  for (int q=0;q<4;++q){
    const int p = q*512 + tid;
    srA[q] = p >> 3;
    scA[q] = ((p & 7) ^ (srA[q] & 7)) * 8;
  }
  int srW[2], scW[2];                 // W: 128x64 = 1024 chunks / 512 thr = 2 each
  #pragma unroll
  for (int q=0;q<2;++q){
    const int p = q*512 + tid;
    srW[q] = p >> 3;
    scW[q] = ((p & 7) ^ (srW[q] & 7)) * 8;
  }
  const unsigned short* Ag = A + (size_t)(mblk*256)*K;
  const unsigned short* Wg = W + (size_t)(nblk*128)*K;

  floatx4 acc[8][2];
  #pragma unroll
  for (int i=0;i<8;++i)
    #pragma unroll
    for (int j=0;j<2;++j) acc[i][j] = (floatx4){0.f,0.f,0.f,0.f};

  // prologue: stage tile0 -> buf0, tile1 -> buf1 (A q0..3 then W q0..1 per tile)
  #pragma unroll
  for (int q=0;q<4;++q)
    gld_lds16(Ag + (size_t)srA[q]*K + scA[q], lds + (q*512 + w*64)*8);
  #pragma unroll
  for (int q=0;q<2;++q)
    gld_lds16(Wg + (size_t)srW[q]*K + scW[q], lds + 16384 + (q*512 + w*64)*8);
  #pragma unroll
  for (int q=0;q<4;++q)
    gld_lds16(Ag + (size_t)srA[q]*K + 64 + scA[q], lds + 24576 + (q*512 + w*64)*8);
  #pragma unroll
  for (int q=0;q<2;++q)
    gld_lds16(Wg + (size_t)srW[q]*K + 64 + scW[q], lds + 24576 + 16384 + (q*512 + w*64)*8);

  int buf = 0;
  for (int t=0; t<nt; ++t){
    unsigned short* As  = lds + buf*24576;
    unsigned short* Wst = As + 16384;
    int nb2 = buf + 2; if (nb2 >= 3) nb2 -= 3;          // buffer of tile t+2
    unsigned short* Sb  = lds + nb2*24576;
    const bool st = (t + 2 < nt);
    const int k2 = (t + 2) << 6;

    if (t == nt-1) asm volatile("s_waitcnt vmcnt(0)" ::: "memory");
    else           asm volatile("s_waitcnt vmcnt(6)" ::: "memory");
    __builtin_amdgcn_s_barrier();

    bf16x8 af[4][2], bf[2][2];
    // ---- P1: read A(mh0) + B; issue A q0,q1 for t+2; MFMA (mh0, kh0)
    #pragma unroll
    for (int i=0;i<4;++i){
      const int row = mrow + i*16 + fr;
      af[i][0] = *(const bf16x8*)&As[swz(row, fq*8)];
      af[i][1] = *(const bf16x8*)&As[swz(row, 32 + fq*8)];
    }
    #pragma unroll
    for (int j=0;j<2;++j){
      const int row = ncol + j*16 + fr;
      bf[j][0] = *(const bf16x8*)&Wst[swz(row, fq*8)];
      bf[j][1] = *(const bf16x8*)&Wst[swz(row, 32 + fq*8)];
    }
    if (st){
      gld_lds16(Ag + (size_t)srA[0]*K + k2 + scA[0], Sb + (0*512 + w*64)*8);
      gld_lds16(Ag + (size_t)srA[1]*K + k2 + scA[1], Sb + (1*512 + w*64)*8);
    }
    __builtin_amdgcn_s_barrier();
    asm volatile("s_waitcnt lgkmcnt(0)" ::: "memory");
    __builtin_amdgcn_sched_barrier(0);
    __builtin_amdgcn_s_setprio(1);
    #pragma unroll
    for (int i=0;i<4;++i)
      #pragma unroll
      for (int j=0;j<2;++j)
        acc[i][j] = __builtin_amdgcn_mfma_f32_16x16x32_bf16(af[i][0], bf[j][0], acc[i][j], 0, 0, 0);
    __builtin_amdgcn_s_setprio(0);
    __builtin_amdgcn_s_barrier();

    // ---- P2: issue A q2,q3; MFMA (mh0, kh1) — register-only
    if (st){
      gld_lds16(Ag + (size_t)srA[2]*K + k2 + scA[2], Sb + (2*512 + w*64)*8);
      gld_lds16(Ag + (size_t)srA[3]*K + k2 + scA[3], Sb + (3*512 + w*64)*8);
    }
    __builtin_amdgcn_s_setprio(1);
    #pragma unroll
    for (int i=0;i<4;++i)
      #pragma unroll
      for (int j=0;j<2;++j)
        acc[i][j] = __builtin_amdgcn_mfma_f32_16x16x32_bf16(af[i][1], bf[j][1], acc[i][j], 0, 0, 0);
    __builtin_amdgcn_s_setprio(0);
    __builtin_amdgcn_s_barrier();

    // ---- P3: read A(mh1); issue W q0,q1; MFMA (mh1, kh0)
    #pragma unroll
    for (int i=0;i<4;++i){
      const int row = mrow + 64 + i*16 + fr;
      af[i][0] = *(const bf16x8*)&As[swz(row, fq*8)];
      af[i][1] = *(const bf16x8*)&As[swz(row, 32 + fq*8)];
    }
    if (st){
      gld_lds16(Wg + (size_t)srW[0]*K + k2 + scW[0], Sb + 16384 + (0*512 + w*64)*8);
      gld_lds16(Wg + (size_t)srW[1]*K + k2 + scW[1], Sb + 16384 + (1*512 + w*64)*8);
    }
    __builtin_amdgcn_s_barrier();
    asm volatile("s_waitcnt lgkmcnt(0)" ::: "memory");
    __builtin_amdgcn_sched_barrier(0);
    __builtin_amdgcn_s_setprio(1);
    #pragma unroll
    for (int i=0;i<4;++i)
      #pragma unroll
      for (int j=0;j<2;++j)
        acc[4+i][j] = __builtin_amdgcn_mfma_f32_16x16x32_bf16(af[i][0], bf[j][0], acc[4+i][j], 0, 0, 0);
    __builtin_amdgcn_s_setprio(0);
    __builtin_amdgcn_s_barrier();

    // ---- P4: MFMA (mh1, kh1) — register-only; next tile entry re-syncs
    __builtin_amdgcn_s_setprio(1);
    #pragma unroll
    for (int i=0;i<4;++i)
      #pragma unroll
      for (int j=0;j<2;++j)
        acc[4+i][j] = __builtin_amdgcn_mfma_f32_16x16x32_bf16(af[i][1], bf[j][1], acc[4+i][j], 0, 0, 0);
    __builtin_amdgcn_s_setprio(0);

    buf = (buf == 2) ? 0 : buf + 1;
  }

  // ---- epilogue: +bias, +resid(bf16) -> f32 (identical math/order to gemm128<3>)
  #pragma unroll
  for (int i=0;i<8;++i){
    const int grow_base = mblk*256 + mrow + (i>>2)*64 + (i&3)*16 + fq*4;
    #pragma unroll
    for (int j=0;j<2;++j){
      const int gcol = nblk*128 + ncol + j*16 + fr;
      const float bias_v = bias[gcol];
      #pragma unroll
      for (int r=0;r<4;++r){
        const size_t o = (size_t)(grow_base + r)*N + gcol;
        outf[o] = bf2f(residb[o]) + acc[i][j][r] + bias_v;
      }
    }
  }
}

// ---------- state scan, chunk-local (LDS-staged; bf16 sloc + f32 chunk ends) ----------
__global__ __launch_bounds__(64) void state_local(
    const unsigned short* __restrict__ proj, const float* __restrict__ sdo,
    unsigned short* __restrict__ slocb, float* __restrict__ Sarr,
    float* __restrict__ sEnd){
  __shared__ __align__(16) unsigned short a_s[4096];
  __shared__ float sv_s[64];
  const int c = blockIdx.x, bh = blockIdx.y, b = bh>>3, h = bh&7, d = threadIdx.x;
  const int t0 = c*CLEN;
  const unsigned short* ap = proj + (size_t)h*PLANE + (size_t)(b*S_+t0)*64;
  #pragma unroll
  for (int q=0;q<8;++q)
    *(float4*)&a_s[(q*64 + d)*8] = *(const float4*)(ap + (size_t)(q*64 + d)*8);
  sv_s[d] = sdo[(size_t)h*ROWS + b*S_+t0+d];
  __syncthreads();
  float s = 0.f, S = 1.f;
  #pragma unroll 4
  for (int j=0;j<CLEN;++j){
    const int t = t0 + j;
    float a  = bf2f(a_s[j*64 + d]);
    float sv = sv_s[j];
    s = sv*s + (1.f-sv)*a;
    S *= sv;
    slocb[((size_t)bh*S_ + t)*64 + d] = f2bf(s);
    if (d==0) Sarr[bh*S_ + t] = S;
  }
  sEnd[((size_t)c*BH + bh)*64 + d] = s;
}

__global__ __launch_bounds__(64) void state_combine(
    const float* __restrict__ sEnd, const float* __restrict__ Sarr,
    float* __restrict__ sinit){
  const int bh = blockIdx.x, d = threadIdx.x;
  float acc = 0.f;
  for (int c=0;c<NCHUNK;++c){
    sinit[((size_t)c*BH + bh)*64 + d] = acc;
    const int te = c*CLEN + CLEN - 1;
    acc = Sarr[bh*S_ + te]*acc + sEnd[((size_t)c*BH + bh)*64 + d];
  }
}

// ---------- pair chunk-local sums via MFMA (2 waves share one unit's LDS) ----------
__global__ __launch_bounds__(128) void pair_localm(
    const unsigned short* __restrict__ proj, const float* __restrict__ pdo,
    const unsigned short* __restrict__ slocb, const float* __restrict__ Sarr,
    const float* __restrict__ sinit, float* __restrict__ pairbuf,
    float* __restrict__ Dprod){
  __shared__ __align__(16) unsigned short Bt[4096];
  __shared__ __align__(16) unsigned short Pt[4096];
  const int c=blockIdx.x, bh=blockIdx.y, b=bh>>3, h=bh&7;
  const int w = threadIdx.x>>6, l = threadIdx.x&63;
  const int t = c*CLEN + l;
  float pd = pdo[(size_t)h*ROWS + b*S_+t];
  float D = pd;
  #pragma unroll
  for (int m=1;m<64;m<<=1){ float o = __shfl_up(D, m); if (l>=m) D *= o; }
  const float Dend = __shfl(D, 63);
  const float cu = (Dend / D) * (1.f - pd);
  if (w==0 && l==63) Dprod[c*BH+bh] = Dend;
  {
    const unsigned short* brow = proj + (size_t)(8+h)*PLANE + (size_t)(b*S_+t)*64;
    const size_t ptm = (size_t)bh*S_ + (l==0 ? t : t-1);
    const unsigned short* srow = slocb + ptm*64;
    const float* initp = sinit + ((size_t)c*BH + bh)*64;
    float sp = 0.f;
    if (l>0) sp = Sarr[ptm];
    #pragma unroll
    for (int e8=w*4; e8<w*4+4; ++e8){
      ushort4 u0 = *(const ushort4*)(brow + e8*8);
      ushort4 u1 = *(const ushort4*)(brow + e8*8 + 4);
      unsigned short vs[8] = {u0.x,u0.y,u0.z,u0.w,u1.x,u1.y,u1.z,u1.w};
      ushort4 s0 = *(const ushort4*)(srow + e8*8);
      ushort4 s1 = *(const ushort4*)(srow + e8*8 + 4);
      unsigned short ss[8] = {s0.x,s0.y,s0.z,s0.w,s1.x,s1.y,s1.z,s1.w};
      float4 i0 = *(const float4*)(initp + e8*8);
      float4 i1 = *(const float4*)(initp + e8*8 + 4);
      float iv[8] = {i0.x,i0.y,i0.z,i0.w,i1.x,i1.y,i1.z,i1.w};
      #pragma unroll
      for (int q=0;q<8;++q){
        const int r = e8*8+q;
        float p = (l==0) ? iv[q] : (sp*iv[q] + bf2f(ss[q]));
        Bt[swz(r, l)] = f2bf(cu * bf2f(vs[q]));
        Pt[swz(r, l)] = f2bf(p);
      }
    }
  }
  __syncthreads();
  const int fr = l & 15, fq = l >> 4;
  floatx4 acc[4][2];
  #pragma unroll
  for (int i=0;i<4;++i)
    #pragma unroll
    for (int jj=0;jj<2;++jj) acc[i][jj] = (floatx4){0.f,0.f,0.f,0.f};
  #pragma unroll
  for (int kh=0;kh<2;++kh){
    bf16x8 af[4], bfr[2];
    #pragma unroll
    for (int i=0;i<4;++i)  af[i]  = *(const bf16x8*)&Bt[swz(i*16+fr, kh*32+fq*8)];
    #pragma unroll
    for (int jj=0;jj<2;++jj) bfr[jj] = *(const bf16x8*)&Pt[swz((w*2+jj)*16+fr, kh*32+fq*8)];
    #pragma unroll
    for (int i=0;i<4;++i)
      #pragma unroll
      for (int jj=0;jj<2;++jj)
        acc[i][jj] = __builtin_amdgcn_mfma_f32_16x16x32_bf16(af[i], bfr[jj], acc[i][jj], 0, 0, 0);
  }
  float* outp = pairbuf + ((size_t)c*BH + bh)*4096;
  #pragma unroll
  for (int i=0;i<4;++i)
    #pragma unroll
    for (int jj=0;jj<2;++jj)
      #pragma unroll
      for (int r=0;r<4;++r)
        outp[(i*16+fq*4+r)*64 + (w*2+jj)*16+fr] = acc[i][jj][r];
}

// prefix combine: read f32 local sums, write bf16 prefix
__global__ __launch_bounds__(256) void pair_combine(
    const float* __restrict__ pairbuf, const float* __restrict__ Dprod,
    unsigned short* __restrict__ pinitb){
  const int idx = blockIdx.x*256 + threadIdx.x;     // 262144
  const int de = idx & 4095, bh = idx >> 12;
  float acc = 0.f;
  for (int c=0;c<NCHUNK;++c){
    const size_t o = ((size_t)c*BH + bh)*4096 + de;
    pinitb[o] = f2bf(acc);
    acc = Dprod[c*BH + bh]*acc + pairbuf[o];
  }
}

// ---------- pair final: masked linear attention via MFMA (2 waves / unit) ----------
__global__ __launch_bounds__(128) void pair_finalm(
    const unsigned short* __restrict__ proj, const float* __restrict__ pdo,
    const unsigned short* __restrict__ slocb, const float* __restrict__ Sarr,
    const float* __restrict__ sinit, const unsigned short* __restrict__ pinitb,
    unsigned short* __restrict__ lcqr){
  __shared__ __align__(16) unsigned short Bt[4096];
  __shared__ __align__(16) unsigned short Tb[4096];
  __shared__ __align__(16) float Dtl[64];
  __shared__ __align__(16) float cudl[64];
  const int c=blockIdx.x, bh=blockIdx.y, b=bh>>3, h=bh&7;
  const int w=threadIdx.x>>6, l=threadIdx.x&63;
  const int t0 = c*CLEN;
  const int trow = t0 + l;
  float pd = pdo[(size_t)h*ROWS + b*S_+trow];
  float D = pd;
  #pragma unroll
  for (int m=1;m<64;m<<=1){ float o = __shfl_up(D, m); if (l>=m) D *= o; }
  if (w==0){ Dtl[l] = D; cudl[l] = (1.f - pd) / D; }
  {
    const unsigned short* brow = proj + (size_t)(8+h)*PLANE + (size_t)(b*S_+trow)*64;
    #pragma unroll
    for (int e8=w*4; e8<w*4+4; ++e8){
      ushort4 u0 = *(const ushort4*)(brow + e8*8);
      ushort4 u1 = *(const ushort4*)(brow + e8*8 + 4);
      unsigned short vs[8] = {u0.x,u0.y,u0.z,u0.w,u1.x,u1.y,u1.z,u1.w};
      #pragma unroll
      for (int q=0;q<8;++q) Bt[swz(e8*8+q, l)] = vs[q];
    }
  }
  __syncthreads();
  const int fr = l & 15, fq = l >> 4;
  const float* initp = sinit + ((size_t)c*BH + bh)*64;
  bf16x8 qf[4][2], pf[2][2];
  #pragma unroll
  for (int i=0;i<4;++i)
    #pragma unroll
    for (int kh=0;kh<2;++kh)
      qf[i][kh] = *(const bf16x8*)(proj + (size_t)(16+h)*PLANE + (size_t)(b*S_ + t0 + i*16 + fr)*64 + kh*32 + fq*8);
  #pragma unroll
  for (int jw=0;jw<2;++jw){
    const int jx = w*2+jw;
    const int tr = t0 + jx*16 + fr;
    const bool first = (jx==0 && fr==0);
    const size_t ptm = (size_t)bh*S_ + (first ? tr : tr-1);
    float sp = 0.f;
    if (!first) sp = Sarr[ptm];
    #pragma unroll
    for (int kh=0;kh<2;++kh){
      bf16x8 sv = *(const bf16x8*)(slocb + ptm*64 + kh*32 + fq*8);
      float4 i0 = *(const float4*)(initp + kh*32 + fq*8);
      float4 i1 = *(const float4*)(initp + kh*32 + fq*8 + 4);
      float iv[8] = {i0.x,i0.y,i0.z,i0.w,i1.x,i1.y,i1.z,i1.w};
      bf16x8 pv;
      #pragma unroll
      for (int e=0;e<8;++e){
        float p = first ? iv[e] : (sp*iv[e] + (float)sv[e]);
        pv[e] = (__bf16)p;
      }
      pf[jw][kh] = pv;
    }
  }
  floatx4 sacc[4][2];
  #pragma unroll
  for (int i=0;i<4;++i)
    #pragma unroll
    for (int jw=0;jw<2;++jw) sacc[i][jw] = (floatx4){0.f,0.f,0.f,0.f};
  #pragma unroll
  for (int kh=0;kh<2;++kh)
    #pragma unroll
    for (int i=0;i<4;++i)
      #pragma unroll
      for (int jw=0;jw<2;++jw)
        sacc[i][jw] = __builtin_amdgcn_mfma_f32_16x16x32_bf16(qf[i][kh], pf[jw][kh], sacc[i][jw], 0, 0, 0);
  float mycud[2];
  #pragma unroll
  for (int jw=0;jw<2;++jw) mycud[jw] = cudl[(w*2+jw)*16+fr];
  #pragma unroll
  for (int i=0;i<4;++i){
    floatx4 dtv = *(const floatx4*)&Dtl[i*16+fq*4];
    #pragma unroll
    for (int jw=0;jw<2;++jw){
      const int uu = (w*2+jw)*16+fr;
      #pragma unroll
      for (int r=0;r<4;++r){
        const int tt = i*16+fq*4+r;
        float v = (uu<=tt) ? (sacc[i][jw][r]*dtv[r])*mycud[jw] : 0.f;
        Tb[swz(tt, uu)] = f2bf(v);
      }
    }
  }
  __syncthreads();
  floatx4 acc[4][2];
  #pragma unroll
  for (int i=0;i<4;++i)
    #pragma unroll
    for (int jw=0;jw<2;++jw) acc[i][jw] = (floatx4){0.f,0.f,0.f,0.f};
  #pragma unroll
  for (int kh=0;kh<2;++kh){
    bf16x8 af[4], bfr[2];
    #pragma unroll
    for (int i=0;i<4;++i)  af[i]  = *(const bf16x8*)&Tb[swz(i*16+fr, kh*32+fq*8)];
    #pragma unroll
    for (int jw=0;jw<2;++jw) bfr[jw] = *(const bf16x8*)&Bt[swz((w*2+jw)*16+fr, kh*32+fq*8)];
    #pragma unroll
    for (int i=0;i<4;++i)
      #pragma unroll
      for (int jw=0;jw<2;++jw)
        acc[i][jw] = __builtin_amdgcn_mfma_f32_16x16x32_bf16(af[i], bfr[jw], acc[i][jw], 0, 0, 0);
  }
  {
    const unsigned short* ib = pinitb + ((size_t)c*BH + bh)*4096;
    #pragma unroll
    for (int kh=0;kh<2;++kh){
      bf16x8 qs[4], inf[2];
      #pragma unroll
      for (int i=0;i<4;++i){
        const float sc = Dtl[i*16+fr];
        #pragma unroll
        for (int e=0;e<8;++e) qs[i][e] = (__bf16)(sc * (float)qf[i][kh][e]);
      }
      #pragma unroll
      for (int jw=0;jw<2;++jw)
        inf[jw] = *(const bf16x8*)(ib + ((w*2+jw)*16+fr)*64 + kh*32 + fq*8);
      #pragma unroll
      for (int i=0;i<4;++i)
        #pragma unroll
        for (int jw=0;jw<2;++jw)
          acc[i][jw] = __builtin_amdgcn_mfma_f32_16x16x32_bf16(qs[i], inf[jw], acc[i][jw], 0, 0, 0);
    }
  }
  __syncthreads();
  #pragma unroll
  for (int i=0;i<4;++i)
    #pragma unroll
    for (int jw=0;jw<2;++jw)
      #pragma unroll
      for (int r=0;r<4;++r)
        Tb[swz(i*16+fq*4+r, (w*2+jw)*16+fr)] = f2bf(acc[i][jw][r]);
  __syncthreads();
  {
    const unsigned short* qrow = proj + (size_t)(24+h)*PLANE + (size_t)(b*S_+trow)*64;
    unsigned short* orow = lcqr + ((size_t)(b*S_+trow))*512 + h*64;
    #pragma unroll
    for (int e8=w*4; e8<w*4+4; ++e8){
      bf16x8 lcv = *(const bf16x8*)&Tb[swz(l, e8*8)];
      ushort4 q0 = *(const ushort4*)(qrow + e8*8);
      ushort4 q1 = *(const ushort4*)(qrow + e8*8 + 4);
      unsigned short qv[8] = {q0.x,q0.y,q0.z,q0.w,q1.x,q1.y,q1.z,q1.w};
      ushort4 o0, o1;
      o0.x = f2bf((float)lcv[0]*bf2f(qv[0]));
      o0.y = f2bf((float)lcv[1]*bf2f(qv[1]));
      o0.z = f2bf((float)lcv[2]*bf2f(qv[2]));
      o0.w = f2bf((float)lcv[3]*bf2f(qv[3]));
      o1.x = f2bf((float)lcv[4]*bf2f(qv[4]));
      o1.y = f2bf((float)lcv[5]*bf2f(qv[5]));
      o1.z = f2bf((float)lcv[6]*bf2f(qv[6]));
      o1.w = f2bf((float)lcv[7]*bf2f(qv[7]));
      *(ushort4*)(orow + e8*8)     = o0;
      *(ushort4*)(orow + e8*8 + 4) = o1;
    }
  }
}

// ---------- launch ----------
extern "C" void kernel_launch(void* const* d_in, const int* in_sizes, int n_in,
                              void* d_out, int out_size, void* d_ws, size_t ws_size,
                              hipStream_t stream){
  (void)in_sizes; (void)n_in; (void)out_size; (void)ws_size;
  const float* x    = (const float*)d_in[0];
  const float* ng   = (const float*)d_in[1];
  const float* nb   = (const float*)d_in[2];
  const float* fng  = (const float*)d_in[3];
  const float* fnb  = (const float*)d_in[4];
  const float* Wa   = (const float*)d_in[5];
  const float* Wb   = (const float*)d_in[6];
  const float* Wql  = (const float*)d_in[7];
  const float* Wqr  = (const float*)d_in[8];
  const float* Wsd  = (const float*)d_in[9];
  const float* bsd  = (const float*)d_in[10];
  const float* Wpd  = (const float*)d_in[11];
  const float* bpd  = (const float*)d_in[12];
  const float* Wout = (const float*)d_in[13];
  const float* W1   = (const float*)d_in[14];
  const float* b1   = (const float*)d_in[15];
  const float* W2   = (const float*)d_in[16];
  const float* b2   = (const float*)d_in[17];
  float* out = (float*)d_out;
  char* ws = (char*)d_ws;

  size_t off = 0;
  auto alloc = [&](size_t bytes)->char*{ char* p = ws + off; off += (bytes + 255) & ~(size_t)255; return p; };
  char* RA = alloc((size_t)ROWS*DM_*2);      // nbf -> lcqr -> nr
  char* RB = alloc((size_t)ROWS*2048*2);     // proj (head-major planes) -> hbuf
  char* RD = alloc((size_t)NCHUNK*BH*4096*4);// pairbuf (f32 local sums)
  char* RE = alloc((size_t)BH*S_*64*4);      // front: slocb(bf16) -> rbufb(bf16); back: pinitb(bf16)
  float* sdo   = (float*)alloc((size_t)ROWS*8*4);
  float* pdo   = (float*)alloc((size_t)ROWS*8*4);
  float* Sarr  = (float*)alloc((size_t)BH*S_*4);
  float* sinit = (float*)alloc((size_t)NCHUNK*BH*64*4);
  float* sEnd  = (float*)alloc((size_t)NCHUNK*BH*64*4);
  float* dprod = (float*)alloc((size_t)NCHUNK*BH*4);
  unsigned short* wcat  = (unsigned short*)alloc((size_t)2048*512*2);
  unsigned short* woutb = (unsigned short*)alloc((size_t)512*512*2);
  unsigned short* w1b   = (unsigned short*)alloc((size_t)2048*512*2);
  unsigned short* w2b   = (unsigned short*)alloc((size_t)512*2048*2);

  unsigned short* nbf   = (unsigned short*)RA;
  unsigned short* lcqr  = (unsigned short*)RA;
  unsigned short* nr    = (unsigned short*)RA;
  unsigned short* proj  = (unsigned short*)RB;
  unsigned short* hbuf  = (unsigned short*)RB;
  float* pairb = (float*)RD;
  unsigned short* slocb  = (unsigned short*)RE;
  unsigned short* rbufb  = (unsigned short*)RE;
  unsigned short* pinitb = (unsigned short*)(RE + (size_t)BH*S_*64*2);

  cvt_weights<<<dim3(3328), dim3(256), 0, stream>>>(Wa,Wb,Wql,Wqr,Wout,W1,W2, wcat,woutb,w1b,w2b);
  ln_gates<<<dim3(ROWS/4), dim3(256), 0, stream>>>(x, ng, nb, Wsd, bsd, Wpd, bpd, nbf, sdo, pdo);
  gemm128<0><<<dim3(128,16), dim3(256), 0, stream>>>(nbf, wcat, nullptr, nullptr, nullptr, nullptr, proj, 2048, 512);
  state_local<<<dim3(NCHUNK,BH), dim3(64), 0, stream>>>(proj, sdo, slocb, Sarr, sEnd);
  state_combine<<<dim3(BH), dim3(64), 0, stream>>>(sEnd, Sarr, sinit);
  pair_localm<<<dim3(NCHUNK,BH), dim3(128), 0, stream>>>(proj, pdo, slocb, Sarr, sinit, pairb, dprod);
  pair_combine<<<dim3(1024), dim3(256), 0, stream>>>(pairb, dprod, pinitb);
  pair_finalm<<<dim3(NCHUNK,BH), dim3(128), 0, stream>>>(proj, pdo, slocb, Sarr, sinit, pinitb, lcqr);
  gemm128<1><<<dim3(128,4), dim3(256), 0, stream>>>(lcqr, woutb, nullptr, x, nullptr, nullptr, rbufb, 512, 512);
  ln_plain<<<dim3(ROWS/4), dim3(256), 0, stream>>>(rbufb, fng, fnb, nr);
  gemm128<2><<<dim3(128,16), dim3(256), 0, stream>>>(nr, w1b, b1, nullptr, nullptr, nullptr, hbuf, 2048, 512);
  // FFN2: 256x128-tile 4-phase pipelined GEMM (nt=32, 1 block/CU, counted vmcnt)
  gemm_ffn2<<<dim3(64,4), dim3(512), 0, stream>>>(hbuf, w2b, b2, rbufb, out, 512, 2048);
}

// Round 11
// 399.452 us; speedup vs baseline: 1.0438x; 1.0107x over previous
//
#include <hip/hip_runtime.h>
#include <cstdint>
#include <cstddef>

// Problem constants
#define B_    8
#define S_    2048
#define DM_   512
#define H_    8
#define SD_   64
#define HID_  2048
#define ROWS  (B_*S_)      // 16384
#define BH    (B_*H_)      // 64
#define NCHUNK 32
#define CLEN   64
#define EPS_  1e-5f
#define PLANE ((size_t)ROWS*64)   // one head-plane of proj: 16384*64 shorts

typedef __bf16 bf16x8 __attribute__((ext_vector_type(8)));
typedef float  floatx4 __attribute__((ext_vector_type(4)));

// proj layout is HEAD-MAJOR: proj[plane][row][64], plane = mat*8 + h.
// Gate layout HEAD-MAJOR: sdo/pdo[h][ROWS].
// pair kernels: 2 waves share one (c,bh) unit's 16KB LDS.
// FFN2: 256x128-tile 4-phase pipeline, nt=32, triple-buffered LDS, counted vmcnt.
// GEMMs use XCD-aware panel-major block swizzle (T1): consecutive wgids on one
// XCD share an A-panel -> panel reuse becomes L2-local (8 non-coherent L2s).

// ---------- small helpers ----------
static __device__ __forceinline__ float bf2f(unsigned short h){
  union { unsigned int u; float f; } v; v.u = ((unsigned int)h) << 16; return v.f;
}
static __device__ __forceinline__ unsigned short f2bf(float f){
  union { float f; unsigned int u; } v; v.f = f;
  unsigned int r = v.u + 0x7fffu + ((v.u >> 16) & 1u);
  return (unsigned short)(r >> 16);
}
static __device__ __forceinline__ float fast_tanh(float x){
  float ax = fabsf(x);
  float e  = __expf(2.f*ax);
  float t  = 1.f - 2.f/(e+1.f);
  return copysignf(t, x);
}
static __device__ __forceinline__ float sigmoidf_(float z){
  return 1.f/(1.f + expf(-z));
}
static __device__ __forceinline__ float gelu_exact(float x){
  return 0.5f*x*(1.f + erff(x*0.70710678118654752440f));
}
static __device__ __forceinline__ void gld_lds16(const unsigned short* g, unsigned short* lds){
  __builtin_amdgcn_global_load_lds(
      (const __attribute__((address_space(1))) void*)g,
      (__attribute__((address_space(3))) void*)lds,
      16, 0, 0);
}
// XOR swizzle for 64-half (128B) rows: 16B chunk kc of row r stored at chunk kc^(r&7)
static __device__ __forceinline__ int swz(int row, int col){
  return row*64 + (((col>>3) ^ (row&7))<<3) + (col&7);
}
// XCD-aware panel-major block remap (bijective; grids divisible by 8).
// Returns wgid such that consecutive wgids on one XCD share an A-panel.
static __device__ __forceinline__ int xcd_wgid(){
  const int lin = blockIdx.y * gridDim.x + blockIdx.x;
  const int cpx = (gridDim.x * gridDim.y) >> 3;
  return (lin & 7) * cpx + (lin >> 3);
}

// ---------- weight fp32 -> bf16 conversion ----------
__global__ __launch_bounds__(256) void cvt_weights(
    const float* __restrict__ wa, const float* __restrict__ wb,
    const float* __restrict__ wql, const float* __restrict__ wqr,
    const float* __restrict__ wout, const float* __restrict__ w1,
    const float* __restrict__ w2,
    unsigned short* __restrict__ wcat, unsigned short* __restrict__ woutb,
    unsigned short* __restrict__ w1b, unsigned short* __restrict__ w2b){
  int i = blockIdx.x*256 + threadIdx.x;   // float4 units, total 851968
  const float* s; unsigned short* d; int base;
  if      (i <  65536){ s=wa;   d=wcat;          base=i; }
  else if (i < 131072){ s=wb;   d=wcat+262144;   base=i-65536; }
  else if (i < 196608){ s=wql;  d=wcat+524288;   base=i-131072; }
  else if (i < 262144){ s=wqr;  d=wcat+786432;   base=i-196608; }
  else if (i < 327680){ s=wout; d=woutb;         base=i-262144; }
  else if (i < 589824){ s=w1;   d=w1b;           base=i-327680; }
  else                { s=w2;   d=w2b;           base=i-589824; }
  float4 v = ((const float4*)s)[base];
  ushort4 o; o.x=f2bf(v.x); o.y=f2bf(v.y); o.z=f2bf(v.z); o.w=f2bf(v.w);
  ((ushort4*)d)[base] = o;
}

// ---------- LN1 + gate heads (4 rows/block, 1 wave each) ----------
__global__ __launch_bounds__(256) void ln_gates(
    const float* __restrict__ x, const float* __restrict__ gam, const float* __restrict__ bet,
    const float* __restrict__ Wsd, const float* __restrict__ bsd,
    const float* __restrict__ Wpd, const float* __restrict__ bpd,
    unsigned short* __restrict__ nbf, float* __restrict__ sdo, float* __restrict__ pdo){
  const int row = blockIdx.x*4 + (threadIdx.x>>6), l = threadIdx.x & 63;
  const float* xr = x + (size_t)row*DM_;
  float4 v0 = ((const float4*)xr)[l*2];
  float4 v1 = ((const float4*)xr)[l*2+1];
  float v[8] = {v0.x,v0.y,v0.z,v0.w,v1.x,v1.y,v1.z,v1.w};
  float s = 0.f;
  #pragma unroll
  for (int i=0;i<8;++i) s += v[i];
  #pragma unroll
  for (int m=1;m<64;m<<=1) s += __shfl_xor(s, m);
  const float mean = s * (1.f/512.f);
  float q = 0.f;
  #pragma unroll
  for (int i=0;i<8;++i){ float d = v[i]-mean; q += d*d; }
  #pragma unroll
  for (int m=1;m<64;m<<=1) q += __shfl_xor(q, m);
  const float rstd = rsqrtf(q*(1.f/512.f) + EPS_);
  float4 g0 = ((const float4*)gam)[l*2], g1 = ((const float4*)gam)[l*2+1];
  float4 b0 = ((const float4*)bet)[l*2], b1 = ((const float4*)bet)[l*2+1];
  float gg[8] = {g0.x,g0.y,g0.z,g0.w,g1.x,g1.y,g1.z,g1.w};
  float bb[8] = {b0.x,b0.y,b0.z,b0.w,b1.x,b1.y,b1.z,b1.w};
  float n[8];
  #pragma unroll
  for (int i=0;i<8;++i) n[i] = (v[i]-mean)*rstd*gg[i] + bb[i];
  ushort4 o0, o1;
  o0.x=f2bf(n[0]); o0.y=f2bf(n[1]); o0.z=f2bf(n[2]); o0.w=f2bf(n[3]);
  o1.x=f2bf(n[4]); o1.y=f2bf(n[5]); o1.z=f2bf(n[6]); o1.w=f2bf(n[7]);
  ((ushort4*)(nbf + (size_t)row*DM_))[l*2]   = o0;
  ((ushort4*)(nbf + (size_t)row*DM_))[l*2+1] = o1;
  float acc[16];
  #pragma unroll
  for (int hh=0; hh<8; ++hh){
    const float4* ws = (const float4*)(Wsd + hh*DM_) + l*2;
    const float4* wp = (const float4*)(Wpd + hh*DM_) + l*2;
    float4 a0=ws[0], a1=ws[1], p0=wp[0], p1=wp[1];
    acc[hh]   = n[0]*a0.x+n[1]*a0.y+n[2]*a0.z+n[3]*a0.w+n[4]*a1.x+n[5]*a1.y+n[6]*a1.z+n[7]*a1.w;
    acc[8+hh] = n[0]*p0.x+n[1]*p0.y+n[2]*p0.z+n[3]*p0.w+n[4]*p1.x+n[5]*p1.y+n[6]*p1.z+n[7]*p1.w;
  }
  #pragma unroll
  for (int k=0;k<16;++k){
    float a = acc[k];
    #pragma unroll
    for (int m=1;m<64;m<<=1) a += __shfl_xor(a, m);
    acc[k] = a;
  }
  if (l==0){
    #pragma unroll
    for (int hh=0; hh<8; ++hh){
      sdo[(size_t)hh*ROWS + row] = sigmoidf_(acc[hh]   + bsd[hh]);
      pdo[(size_t)hh*ROWS + row] = sigmoidf_(acc[8+hh] + bpd[hh]);
    }
  }
}

// ---------- plain LN (FFN), bf16 input (4 rows/block) ----------
__global__ __launch_bounds__(256) void ln_plain(
    const unsigned short* __restrict__ xb, const float* __restrict__ gam, const float* __restrict__ bet,
    unsigned short* __restrict__ ob){
  const int row = blockIdx.x*4 + (threadIdx.x>>6), l = threadIdx.x & 63;
  const unsigned short* xr = xb + (size_t)row*DM_ + l*8;
  ushort4 u0 = *(const ushort4*)xr;
  ushort4 u1 = *(const ushort4*)(xr+4);
  float v[8] = {bf2f(u0.x),bf2f(u0.y),bf2f(u0.z),bf2f(u0.w),
                bf2f(u1.x),bf2f(u1.y),bf2f(u1.z),bf2f(u1.w)};
  float s = 0.f;
  #pragma unroll
  for (int i=0;i<8;++i) s += v[i];
  #pragma unroll
  for (int m=1;m<64;m<<=1) s += __shfl_xor(s, m);
  const float mean = s * (1.f/512.f);
  float q = 0.f;
  #pragma unroll
  for (int i=0;i<8;++i){ float d = v[i]-mean; q += d*d; }
  #pragma unroll
  for (int m=1;m<64;m<<=1) q += __shfl_xor(q, m);
  const float rstd = rsqrtf(q*(1.f/512.f) + EPS_);
  float4 g0 = ((const float4*)gam)[l*2], g1 = ((const float4*)gam)[l*2+1];
  float4 b0 = ((const float4*)bet)[l*2], b1 = ((const float4*)bet)[l*2+1];
  float gg[8] = {g0.x,g0.y,g0.z,g0.w,g1.x,g1.y,g1.z,g1.w};
  float bb[8] = {b0.x,b0.y,b0.z,b0.w,b1.x,b1.y,b1.z,b1.w};
  ushort4 o0, o1;
  o0.x=f2bf((v[0]-mean)*rstd*gg[0]+bb[0]); o0.y=f2bf((v[1]-mean)*rstd*gg[1]+bb[1]);
  o0.z=f2bf((v[2]-mean)*rstd*gg[2]+bb[2]); o0.w=f2bf((v[3]-mean)*rstd*gg[3]+bb[3]);
  o1.x=f2bf((v[4]-mean)*rstd*gg[4]+bb[4]); o1.y=f2bf((v[5]-mean)*rstd*gg[5]+bb[5]);
  o1.z=f2bf((v[6]-mean)*rstd*gg[6]+bb[6]); o1.w=f2bf((v[7]-mean)*rstd*gg[7]+bb[7]);
  ((ushort4*)(ob + (size_t)row*DM_))[l*2]   = o0;
  ((ushort4*)(ob + (size_t)row*DM_))[l*2+1] = o1;
}

// ---------- 128x128-tile GEMM, BK=64, single-buffered, XCD panel-major swizzle ----------
// MODE 0: tanh -> bf16 HEAD-MAJOR planes (proj); 1: +resid(f32) -> bf16;
// 2: +bias,gelu -> bf16; 3: +bias+resid(bf16) -> f32
template<int MODE>
__global__ __launch_bounds__(256) void gemm128(
    const unsigned short* __restrict__ A, const unsigned short* __restrict__ W,
    const float* __restrict__ bias, const float* __restrict__ residf,
    const unsigned short* __restrict__ residb,
    float* __restrict__ outf, unsigned short* __restrict__ outb,
    int N, int K){
  __shared__ __align__(16) unsigned short As[128*64];
  __shared__ __align__(16) unsigned short Ws[128*64];
  const int tid  = threadIdx.x;
  const int w    = tid >> 6;
  const int lane = tid & 63;
  // XCD swizzle: consecutive wgids (same XCD) share mblk -> A-panel L2-local
  const int wgid = xcd_wgid();
  const int mblk = wgid / (int)gridDim.y;
  const int nblk = wgid % (int)gridDim.y;
  const int mrow = (w >> 1) * 64;
  const int ncol = (w & 1) * 64;
  const int fr = lane & 15, fq = lane >> 4;

  int srow[4], scol[4];
  #pragma unroll
  for (int q=0;q<4;++q){
    const int p = q*256 + w*64 + lane;
    srow[q] = p >> 3;
    scol[q] = ((p & 7) ^ (srow[q] & 7)) * 8;
  }

  floatx4 acc[4][4];
  #pragma unroll
  for (int i=0;i<4;++i)
    #pragma unroll
    for (int j=0;j<4;++j)
      acc[i][j] = (floatx4){0.f,0.f,0.f,0.f};

  for (int k0=0; k0<K; k0+=64){
    #pragma unroll
    for (int q=0;q<4;++q){
      gld_lds16(A + (size_t)(mblk*128 + srow[q])*K + k0 + scol[q], As + (q*256 + w*64)*8);
      gld_lds16(W + (size_t)(nblk*128 + srow[q])*K + k0 + scol[q], Ws + (q*256 + w*64)*8);
    }
    __syncthreads();
    #pragma unroll
    for (int kh=0;kh<2;++kh){
      bf16x8 af[4], bf[4];
      #pragma unroll
      for (int i=0;i<4;++i) af[i] = *(const bf16x8*)&As[swz(mrow + i*16 + fr, kh*32 + fq*8)];
      #pragma unroll
      for (int j=0;j<4;++j) bf[j] = *(const bf16x8*)&Ws[swz(ncol + j*16 + fr, kh*32 + fq*8)];
      #pragma unroll
      for (int i=0;i<4;++i)
        #pragma unroll
        for (int j=0;j<4;++j)
          acc[i][j] = __builtin_amdgcn_mfma_f32_16x16x32_bf16(af[i], bf[j], acc[i][j], 0, 0, 0);
    }
    __syncthreads();
  }

  #pragma unroll
  for (int i=0;i<4;++i){
    const int grow_base = mblk*128 + mrow + i*16 + fq*4;
    #pragma unroll
    for (int j=0;j<4;++j){
      const int gcol = nblk*128 + ncol + j*16 + fr;
      float bias_v = 0.f;
      if (MODE==2 || MODE==3) bias_v = bias[gcol];
      #pragma unroll
      for (int r=0;r<4;++r){
        float v = acc[i][j][r];
        if (MODE==0){
          const size_t o = (size_t)(gcol>>6)*PLANE + (size_t)(grow_base + r)*64 + (gcol & 63);
          outb[o] = f2bf(fast_tanh(v));
        } else {
          const size_t o = (size_t)(grow_base + r)*N + gcol;
          if      (MODE==1) outb[o] = f2bf(residf[o] + v);
          else if (MODE==2) outb[o] = f2bf(gelu_exact(v + bias_v));
          else              outf[o] = bf2f(residb[o]) + v + bias_v;
        }
      }
    }
  }
}

// ---------- FFN2 GEMM: 256x128-tile, 4-phase, triple-buffered, counted vmcnt ----------
// (round-10: neutral vs gemm128<3> -> barrier drain is NOT the limit; kept since <= baseline.)
// XCD panel-major swizzle added: 4 nblk sharers of each 1MB A-panel co-resident on one XCD.
__global__ __launch_bounds__(512, 2) void gemm_ffn2(
    const unsigned short* __restrict__ A, const unsigned short* __restrict__ W,
    const float* __restrict__ bias, const unsigned short* __restrict__ residb,
    float* __restrict__ outf, int N, int K){
  __shared__ __align__(16) unsigned short lds[73728];   // 144 KB
  const int tid  = threadIdx.x;
  const int w    = tid >> 6;          // wave 0..7
  const int lane = tid & 63;
  const int mrow = (w >> 2) * 128;    // wave M-base
  const int ncol = (w & 3) * 32;      // wave N-base
  const int fr = lane & 15, fq = lane >> 4;
  const int wgid = xcd_wgid();
  const int mblk = wgid >> 2;         // gridDim.y == 4
  const int nblk = wgid & 3;
  const int nt = K >> 6;              // 32

  int srA[4], scA[4];                 // A: 256x64 = 2048 chunks / 512 thr = 4 each
  #pragma unroll
  for (int q=0;q<4;++q){
    const int p = q*512 + tid;
    srA[q] = p >> 3;
    scA[q] = ((p & 7) ^ (srA[q] & 7)) * 8;
  }
  int srW[2], scW[2];                 // W: 128x64 = 1024 chunks / 512 thr = 2 each
  #pragma unroll
  for (int q=0;q<2;++q){
    const int p = q*512 + tid;
    srW[q] = p >> 3;
    scW[q] = ((p & 7) ^ (srW[q] & 7)) * 8;
  }
  const unsigned short* Ag = A + (size_t)(mblk*256)*K;
  const unsigned short* Wg = W + (size_t)(nblk*128)*K;

  floatx4 acc[8][2];
  #pragma unroll
  for (int i=0;i<8;++i)
    #pragma unroll
    for (int j=0;j<2;++j) acc[i][j] = (floatx4){0.f,0.f,0.f,0.f};

  // prologue: stage tile0 -> buf0, tile1 -> buf1 (A q0..3 then W q0..1 per tile)
  #pragma unroll
  for (int q=0;q<4;++q)
    gld_lds16(Ag + (size_t)srA[q]*K + scA[q], lds + (q*512 + w*64)*8);
  #pragma unroll
  for (int q=0;q<2;++q)
    gld_lds16(Wg + (size_t)srW[q]*K + scW[q], lds + 16384 + (q*512 + w*64)*8);
  #pragma unroll
  for (int q=0;q<4;++q)
    gld_lds16(Ag + (size_t)srA[q]*K + 64 + scA[q], lds + 24576 + (q*512 + w*64)*8);
  #pragma unroll
  for (int q=0;q<2;++q)
    gld_lds16(Wg + (size_t)srW[q]*K + 64 + scW[q], lds + 24576 + 16384 + (q*512 + w*64)*8);

  int buf = 0;
  for (int t=0; t<nt; ++t){
    unsigned short* As  = lds + buf*24576;
    unsigned short* Wst = As + 16384;
    int nb2 = buf + 2; if (nb2 >= 3) nb2 -= 3;          // buffer of tile t+2
    unsigned short* Sb  = lds + nb2*24576;
    const bool st = (t + 2 < nt);
    const int k2 = (t + 2) << 6;

    if (t == nt-1) asm volatile("s_waitcnt vmcnt(0)" ::: "memory");
    else           asm volatile("s_waitcnt vmcnt(6)" ::: "memory");
    __builtin_amdgcn_s_barrier();

    bf16x8 af[4][2], bf[2][2];
    // ---- P1: read A(mh0) + B; issue A q0,q1 for t+2; MFMA (mh0, kh0)
    #pragma unroll
    for (int i=0;i<4;++i){
      const int row = mrow + i*16 + fr;
      af[i][0] = *(const bf16x8*)&As[swz(row, fq*8)];
      af[i][1] = *(const bf16x8*)&As[swz(row, 32 + fq*8)];
    }
    #pragma unroll
    for (int j=0;j<2;++j){
      const int row = ncol + j*16 + fr;
      bf[j][0] = *(const bf16x8*)&Wst[swz(row, fq*8)];
      bf[j][1] = *(const bf16x8*)&Wst[swz(row, 32 + fq*8)];
    }
    if (st){
      gld_lds16(Ag + (size_t)srA[0]*K + k2 + scA[0], Sb + (0*512 + w*64)*8);
      gld_lds16(Ag + (size_t)srA[1]*K + k2 + scA[1], Sb + (1*512 + w*64)*8);
    }
    __builtin_amdgcn_s_barrier();
    asm volatile("s_waitcnt lgkmcnt(0)" ::: "memory");
    __builtin_amdgcn_sched_barrier(0);
    __builtin_amdgcn_s_setprio(1);
    #pragma unroll
    for (int i=0;i<4;++i)
      #pragma unroll
      for (int j=0;j<2;++j)
        acc[i][j] = __builtin_amdgcn_mfma_f32_16x16x32_bf16(af[i][0], bf[j][0], acc[i][j], 0, 0, 0);
    __builtin_amdgcn_s_setprio(0);
    __builtin_amdgcn_s_barrier();

    // ---- P2: issue A q2,q3; MFMA (mh0, kh1) — register-only
    if (st){
      gld_lds16(Ag + (size_t)srA[2]*K + k2 + scA[2], Sb + (2*512 + w*64)*8);
      gld_lds16(Ag + (size_t)srA[3]*K + k2 + scA[3], Sb + (3*512 + w*64)*8);
    }
    __builtin_amdgcn_s_setprio(1);
    #pragma unroll
    for (int i=0;i<4;++i)
      #pragma unroll
      for (int j=0;j<2;++j)
        acc[i][j] = __builtin_amdgcn_mfma_f32_16x16x32_bf16(af[i][1], bf[j][1], acc[i][j], 0, 0, 0);
    __builtin_amdgcn_s_setprio(0);
    __builtin_amdgcn_s_barrier();

    // ---- P3: read A(mh1); issue W q0,q1; MFMA (mh1, kh0)
    #pragma unroll
    for (int i=0;i<4;++i){
      const int row = mrow + 64 + i*16 + fr;
      af[i][0] = *(const bf16x8*)&As[swz(row, fq*8)];
      af[i][1] = *(const bf16x8*)&As[swz(row, 32 + fq*8)];
    }
    if (st){
      gld_lds16(Wg + (size_t)srW[0]*K + k2 + scW[0], Sb + 16384 + (0*512 + w*64)*8);
      gld_lds16(Wg + (size_t)srW[1]*K + k2 + scW[1], Sb + 16384 + (1*512 + w*64)*8);
    }
    __builtin_amdgcn_s_barrier();
    asm volatile("s_waitcnt lgkmcnt(0)" ::: "memory");
    __builtin_amdgcn_sched_barrier(0);
    __builtin_amdgcn_s_setprio(1);
    #pragma unroll
    for (int i=0;i<4;++i)
      #pragma unroll
      for (int j=0;j<2;++j)
        acc[4+i][j] = __builtin_amdgcn_mfma_f32_16x16x32_bf16(af[i][0], bf[j][0], acc[4+i][j], 0, 0, 0);
    __builtin_amdgcn_s_setprio(0);
    __builtin_amdgcn_s_barrier();

    // ---- P4: MFMA (mh1, kh1) — register-only; next tile entry re-syncs
    __builtin_amdgcn_s_setprio(1);
    #pragma unroll
    for (int i=0;i<4;++i)
      #pragma unroll
      for (int j=0;j<2;++j)
        acc[4+i][j] = __builtin_amdgcn_mfma_f32_16x16x32_bf16(af[i][1], bf[j][1], acc[4+i][j], 0, 0, 0);
    __builtin_amdgcn_s_setprio(0);

    buf = (buf == 2) ? 0 : buf + 1;
  }

  // ---- epilogue: +bias, +resid(bf16) -> f32 (identical math/order to gemm128<3>)
  #pragma unroll
  for (int i=0;i<8;++i){
    const int grow_base = mblk*256 + mrow + (i>>2)*64 + (i&3)*16 + fq*4;
    #pragma unroll
    for (int j=0;j<2;++j){
      const int gcol = nblk*128 + ncol + j*16 + fr;
      const float bias_v = bias[gcol];
      #pragma unroll
      for (int r=0;r<4;++r){
        const size_t o = (size_t)(grow_base + r)*N + gcol;
        outf[o] = bf2f(residb[o]) + acc[i][j][r] + bias_v;
      }
    }
  }
}

// ---------- state scan, chunk-local (LDS-staged; bf16 sloc + f32 chunk ends) ----------
__global__ __launch_bounds__(64) void state_local(
    const unsigned short* __restrict__ proj, const float* __restrict__ sdo,
    unsigned short* __restrict__ slocb, float* __restrict__ Sarr,
    float* __restrict__ sEnd){
  __shared__ __align__(16) unsigned short a_s[4096];
  __shared__ float sv_s[64];
  const int c = blockIdx.x, bh = blockIdx.y, b = bh>>3, h = bh&7, d = threadIdx.x;
  const int t0 = c*CLEN;
  const unsigned short* ap = proj + (size_t)h*PLANE + (size_t)(b*S_+t0)*64;
  #pragma unroll
  for (int q=0;q<8;++q)
    *(float4*)&a_s[(q*64 + d)*8] = *(const float4*)(ap + (size_t)(q*64 + d)*8);
  sv_s[d] = sdo[(size_t)h*ROWS + b*S_+t0+d];
  __syncthreads();
  float s = 0.f, S = 1.f;
  #pragma unroll 4
  for (int j=0;j<CLEN;++j){
    const int t = t0 + j;
    float a  = bf2f(a_s[j*64 + d]);
    float sv = sv_s[j];
    s = sv*s + (1.f-sv)*a;
    S *= sv;
    slocb[((size_t)bh*S_ + t)*64 + d] = f2bf(s);
    if (d==0) Sarr[bh*S_ + t] = S;
  }
  sEnd[((size_t)c*BH + bh)*64 + d] = s;
}

__global__ __launch_bounds__(64) void state_combine(
    const float* __restrict__ sEnd, const float* __restrict__ Sarr,
    float* __restrict__ sinit){
  const int bh = blockIdx.x, d = threadIdx.x;
  float acc = 0.f;
  for (int c=0;c<NCHUNK;++c){
    sinit[((size_t)c*BH + bh)*64 + d] = acc;
    const int te = c*CLEN + CLEN - 1;
    acc = Sarr[bh*S_ + te]*acc + sEnd[((size_t)c*BH + bh)*64 + d];
  }
}

// ---------- pair chunk-local sums via MFMA (2 waves share one unit's LDS) ----------
__global__ __launch_bounds__(128) void pair_localm(
    const unsigned short* __restrict__ proj, const float* __restrict__ pdo,
    const unsigned short* __restrict__ slocb, const float* __restrict__ Sarr,
    const float* __restrict__ sinit, float* __restrict__ pairbuf,
    float* __restrict__ Dprod){
  __shared__ __align__(16) unsigned short Bt[4096];
  __shared__ __align__(16) unsigned short Pt[4096];
  const int c=blockIdx.x, bh=blockIdx.y, b=bh>>3, h=bh&7;
  const int w = threadIdx.x>>6, l = threadIdx.x&63;
  const int t = c*CLEN + l;
  float pd = pdo[(size_t)h*ROWS + b*S_+t];
  float D = pd;
  #pragma unroll
  for (int m=1;m<64;m<<=1){ float o = __shfl_up(D, m); if (l>=m) D *= o; }
  const float Dend = __shfl(D, 63);
  const float cu = (Dend / D) * (1.f - pd);
  if (w==0 && l==63) Dprod[c*BH+bh] = Dend;
  {
    const unsigned short* brow = proj + (size_t)(8+h)*PLANE + (size_t)(b*S_+t)*64;
    const size_t ptm = (size_t)bh*S_ + (l==0 ? t : t-1);
    const unsigned short* srow = slocb + ptm*64;
    const float* initp = sinit + ((size_t)c*BH + bh)*64;
    float sp = 0.f;
    if (l>0) sp = Sarr[ptm];
    #pragma unroll
    for (int e8=w*4; e8<w*4+4; ++e8){
      ushort4 u0 = *(const ushort4*)(brow + e8*8);
      ushort4 u1 = *(const ushort4*)(brow + e8*8 + 4);
      unsigned short vs[8] = {u0.x,u0.y,u0.z,u0.w,u1.x,u1.y,u1.z,u1.w};
      ushort4 s0 = *(const ushort4*)(srow + e8*8);
      ushort4 s1 = *(const ushort4*)(srow + e8*8 + 4);
      unsigned short ss[8] = {s0.x,s0.y,s0.z,s0.w,s1.x,s1.y,s1.z,s1.w};
      float4 i0 = *(const float4*)(initp + e8*8);
      float4 i1 = *(const float4*)(initp + e8*8 + 4);
      float iv[8] = {i0.x,i0.y,i0.z,i0.w,i1.x,i1.y,i1.z,i1.w};
      #pragma unroll
      for (int q=0;q<8;++q){
        const int r = e8*8+q;
        float p = (l==0) ? iv[q] : (sp*iv[q] + bf2f(ss[q]));
        Bt[swz(r, l)] = f2bf(cu * bf2f(vs[q]));
        Pt[swz(r, l)] = f2bf(p);
      }
    }
  }
  __syncthreads();
  const int fr = l & 15, fq = l >> 4;
  floatx4 acc[4][2];
  #pragma unroll
  for (int i=0;i<4;++i)
    #pragma unroll
    for (int jj=0;jj<2;++jj) acc[i][jj] = (floatx4){0.f,0.f,0.f,0.f};
  #pragma unroll
  for (int kh=0;kh<2;++kh){
    bf16x8 af[4], bfr[2];
    #pragma unroll
    for (int i=0;i<4;++i)  af[i]  = *(const bf16x8*)&Bt[swz(i*16+fr, kh*32+fq*8)];
    #pragma unroll
    for (int jj=0;jj<2;++jj) bfr[jj] = *(const bf16x8*)&Pt[swz((w*2+jj)*16+fr, kh*32+fq*8)];
    #pragma unroll
    for (int i=0;i<4;++i)
      #pragma unroll
      for (int jj=0;jj<2;++jj)
        acc[i][jj] = __builtin_amdgcn_mfma_f32_16x16x32_bf16(af[i], bfr[jj], acc[i][jj], 0, 0, 0);
  }
  float* outp = pairbuf + ((size_t)c*BH + bh)*4096;
  #pragma unroll
  for (int i=0;i<4;++i)
    #pragma unroll
    for (int jj=0;jj<2;++jj)
      #pragma unroll
      for (int r=0;r<4;++r)
        outp[(i*16+fq*4+r)*64 + (w*2+jj)*16+fr] = acc[i][jj][r];
}

// prefix combine: read f32 local sums, write bf16 prefix
__global__ __launch_bounds__(256) void pair_combine(
    const float* __restrict__ pairbuf, const float* __restrict__ Dprod,
    unsigned short* __restrict__ pinitb){
  const int idx = blockIdx.x*256 + threadIdx.x;     // 262144
  const int de = idx & 4095, bh = idx >> 12;
  float acc = 0.f;
  for (int c=0;c<NCHUNK;++c){
    const size_t o = ((size_t)c*BH + bh)*4096 + de;
    pinitb[o] = f2bf(acc);
    acc = Dprod[c*BH + bh]*acc + pairbuf[o];
  }
}

// ---------- pair final: masked linear attention via MFMA (2 waves / unit) ----------
__global__ __launch_bounds__(128) void pair_finalm(
    const unsigned short* __restrict__ proj, const float* __restrict__ pdo,
    const unsigned short* __restrict__ slocb, const float* __restrict__ Sarr,
    const float* __restrict__ sinit, const unsigned short* __restrict__ pinitb,
    unsigned short* __restrict__ lcqr){
  __shared__ __align__(16) unsigned short Bt[4096];
  __shared__ __align__(16) unsigned short Tb[4096];
  __shared__ __align__(16) float Dtl[64];
  __shared__ __align__(16) float cudl[64];
  const int c=blockIdx.x, bh=blockIdx.y, b=bh>>3, h=bh&7;
  const int w=threadIdx.x>>6, l=threadIdx.x&63;
  const int t0 = c*CLEN;
  const int trow = t0 + l;
  float pd = pdo[(size_t)h*ROWS + b*S_+trow];
  float D = pd;
  #pragma unroll
  for (int m=1;m<64;m<<=1){ float o = __shfl_up(D, m); if (l>=m) D *= o; }
  if (w==0){ Dtl[l] = D; cudl[l] = (1.f - pd) / D; }
  {
    const unsigned short* brow = proj + (size_t)(8+h)*PLANE + (size_t)(b*S_+trow)*64;
    #pragma unroll
    for (int e8=w*4; e8<w*4+4; ++e8){
      ushort4 u0 = *(const ushort4*)(brow + e8*8);
      ushort4 u1 = *(const ushort4*)(brow + e8*8 + 4);
      unsigned short vs[8] = {u0.x,u0.y,u0.z,u0.w,u1.x,u1.y,u1.z,u1.w};
      #pragma unroll
      for (int q=0;q<8;++q) Bt[swz(e8*8+q, l)] = vs[q];
    }
  }
  __syncthreads();
  const int fr = l & 15, fq = l >> 4;
  const float* initp = sinit + ((size_t)c*BH + bh)*64;
  bf16x8 qf[4][2], pf[2][2];
  #pragma unroll
  for (int i=0;i<4;++i)
    #pragma unroll
    for (int kh=0;kh<2;++kh)
      qf[i][kh] = *(const bf16x8*)(proj + (size_t)(16+h)*PLANE + (size_t)(b*S_ + t0 + i*16 + fr)*64 + kh*32 + fq*8);
  #pragma unroll
  for (int jw=0;jw<2;++jw){
    const int jx = w*2+jw;
    const int tr = t0 + jx*16 + fr;
    const bool first = (jx==0 && fr==0);
    const size_t ptm = (size_t)bh*S_ + (first ? tr : tr-1);
    float sp = 0.f;
    if (!first) sp = Sarr[ptm];
    #pragma unroll
    for (int kh=0;kh<2;++kh){
      bf16x8 sv = *(const bf16x8*)(slocb + ptm*64 + kh*32 + fq*8);
      float4 i0 = *(const float4*)(initp + kh*32 + fq*8);
      float4 i1 = *(const float4*)(initp + kh*32 + fq*8 + 4);
      float iv[8] = {i0.x,i0.y,i0.z,i0.w,i1.x,i1.y,i1.z,i1.w};
      bf16x8 pv;
      #pragma unroll
      for (int e=0;e<8;++e){
        float p = first ? iv[e] : (sp*iv[e] + (float)sv[e]);
        pv[e] = (__bf16)p;
      }
      pf[jw][kh] = pv;
    }
  }
  floatx4 sacc[4][2];
  #pragma unroll
  for (int i=0;i<4;++i)
    #pragma unroll
    for (int jw=0;jw<2;++jw) sacc[i][jw] = (floatx4){0.f,0.f,0.f,0.f};
  #pragma unroll
  for (int kh=0;kh<2;++kh)
    #pragma unroll
    for (int i=0;i<4;++i)
      #pragma unroll
      for (int jw=0;jw<2;++jw)
        sacc[i][jw] = __builtin_amdgcn_mfma_f32_16x16x32_bf16(qf[i][kh], pf[jw][kh], sacc[i][jw], 0, 0, 0);
  float mycud[2];
  #pragma unroll
  for (int jw=0;jw<2;++jw) mycud[jw] = cudl[(w*2+jw)*16+fr];
  #pragma unroll
  for (int i=0;i<4;++i){
    floatx4 dtv = *(const floatx4*)&Dtl[i*16+fq*4];
    #pragma unroll
    for (int jw=0;jw<2;++jw){
      const int uu = (w*2+jw)*16+fr;
      #pragma unroll
      for (int r=0;r<4;++r){
        const int tt = i*16+fq*4+r;
        float v = (uu<=tt) ? (sacc[i][jw][r]*dtv[r])*mycud[jw] : 0.f;
        Tb[swz(tt, uu)] = f2bf(v);
      }
    }
  }
  __syncthreads();
  floatx4 acc[4][2];
  #pragma unroll
  for (int i=0;i<4;++i)
    #pragma unroll
    for (int jw=0;jw<2;++jw) acc[i][jw] = (floatx4){0.f,0.f,0.f,0.f};
  #pragma unroll
  for (int kh=0;kh<2;++kh){
    bf16x8 af[4], bfr[2];
    #pragma unroll
    for (int i=0;i<4;++i)  af[i]  = *(const bf16x8*)&Tb[swz(i*16+fr, kh*32+fq*8)];
    #pragma unroll
    for (int jw=0;jw<2;++jw) bfr[jw] = *(const bf16x8*)&Bt[swz((w*2+jw)*16+fr, kh*32+fq*8)];
    #pragma unroll
    for (int i=0;i<4;++i)
      #pragma unroll
      for (int jw=0;jw<2;++jw)
        acc[i][jw] = __builtin_amdgcn_mfma_f32_16x16x32_bf16(af[i], bfr[jw], acc[i][jw], 0, 0, 0);
  }
  {
    const unsigned short* ib = pinitb + ((size_t)c*BH + bh)*4096;
    #pragma unroll
    for (int kh=0;kh<2;++kh){
      bf16x8 qs[4], inf[2];
      #pragma unroll
      for (int i=0;i<4;++i){
        const float sc = Dtl[i*16+fr];
        #pragma unroll
        for (int e=0;e<8;++e) qs[i][e] = (__bf16)(sc * (float)qf[i][kh][e]);
      }
      #pragma unroll
      for (int jw=0;jw<2;++jw)
        inf[jw] = *(const bf16x8*)(ib + ((w*2+jw)*16+fr)*64 + kh*32 + fq*8);
      #pragma unroll
      for (int i=0;i<4;++i)
        #pragma unroll
        for (int jw=0;jw<2;++jw)
          acc[i][jw] = __builtin_amdgcn_mfma_f32_16x16x32_bf16(qs[i], inf[jw], acc[i][jw], 0, 0, 0);
    }
  }
  __syncthreads();
  #pragma unroll
  for (int i=0;i<4;++i)
    #pragma unroll
    for (int jw=0;jw<2;++jw)
      #pragma unroll
      for (int r=0;r<4;++r)
        Tb[swz(i*16+fq*4+r, (w*2+jw)*16+fr)] = f2bf(acc[i][jw][r]);
  __syncthreads();
  {
    const unsigned short* qrow = proj + (size_t)(24+h)*PLANE + (size_t)(b*S_+trow)*64;
    unsigned short* orow = lcqr + ((size_t)(b*S_+trow))*512 + h*64;
    #pragma unroll
    for (int e8=w*4; e8<w*4+4; ++e8){
      bf16x8 lcv = *(const bf16x8*)&Tb[swz(l, e8*8)];
      ushort4 q0 = *(const ushort4*)(qrow + e8*8);
      ushort4 q1 = *(const ushort4*)(qrow + e8*8 + 4);
      unsigned short qv[8] = {q0.x,q0.y,q0.z,q0.w,q1.x,q1.y,q1.z,q1.w};
      ushort4 o0, o1;
      o0.x = f2bf((float)lcv[0]*bf2f(qv[0]));
      o0.y = f2bf((float)lcv[1]*bf2f(qv[1]));
      o0.z = f2bf((float)lcv[2]*bf2f(qv[2]));
      o0.w = f2bf((float)lcv[3]*bf2f(qv[3]));
      o1.x = f2bf((float)lcv[4]*bf2f(qv[4]));
      o1.y = f2bf((float)lcv[5]*bf2f(qv[5]));
      o1.z = f2bf((float)lcv[6]*bf2f(qv[6]));
      o1.w = f2bf((float)lcv[7]*bf2f(qv[7]));
      *(ushort4*)(orow + e8*8)     = o0;
      *(ushort4*)(orow + e8*8 + 4) = o1;
    }
  }
}

// ---------- launch ----------
extern "C" void kernel_launch(void* const* d_in, const int* in_sizes, int n_in,
                              void* d_out, int out_size, void* d_ws, size_t ws_size,
                              hipStream_t stream){
  (void)in_sizes; (void)n_in; (void)out_size; (void)ws_size;
  const float* x    = (const float*)d_in[0];
  const float* ng   = (const float*)d_in[1];
  const float* nb   = (const float*)d_in[2];
  const float* fng  = (const float*)d_in[3];
  const float* fnb  = (const float*)d_in[4];
  const float* Wa   = (const float*)d_in[5];
  const float* Wb   = (const float*)d_in[6];
  const float* Wql  = (const float*)d_in[7];
  const float* Wqr  = (const float*)d_in[8];
  const float* Wsd  = (const float*)d_in[9];
  const float* bsd  = (const float*)d_in[10];
  const float* Wpd  = (const float*)d_in[11];
  const float* bpd  = (const float*)d_in[12];
  const float* Wout = (const float*)d_in[13];
  const float* W1   = (const float*)d_in[14];
  const float* b1   = (const float*)d_in[15];
  const float* W2   = (const float*)d_in[16];
  const float* b2   = (const float*)d_in[17];
  float* out = (float*)d_out;
  char* ws = (char*)d_ws;

  size_t off = 0;
  auto alloc = [&](size_t bytes)->char*{ char* p = ws + off; off += (bytes + 255) & ~(size_t)255; return p; };
  char* RA = alloc((size_t)ROWS*DM_*2);      // nbf -> lcqr -> nr
  char* RB = alloc((size_t)ROWS*2048*2);     // proj (head-major planes) -> hbuf
  char* RD = alloc((size_t)NCHUNK*BH*4096*4);// pairbuf (f32 local sums)
  char* RE = alloc((size_t)BH*S_*64*4);      // front: slocb(bf16) -> rbufb(bf16); back: pinitb(bf16)
  float* sdo   = (float*)alloc((size_t)ROWS*8*4);
  float* pdo   = (float*)alloc((size_t)ROWS*8*4);
  float* Sarr  = (float*)alloc((size_t)BH*S_*4);
  float* sinit = (float*)alloc((size_t)NCHUNK*BH*64*4);
  float* sEnd  = (float*)alloc((size_t)NCHUNK*BH*64*4);
  float* dprod = (float*)alloc((size_t)NCHUNK*BH*4);
  unsigned short* wcat  = (unsigned short*)alloc((size_t)2048*512*2);
  unsigned short* woutb = (unsigned short*)alloc((size_t)512*512*2);
  unsigned short* w1b   = (unsigned short*)alloc((size_t)2048*512*2);
  unsigned short* w2b   = (unsigned short*)alloc((size_t)512*2048*2);

  unsigned short* nbf   = (unsigned short*)RA;
  unsigned short* lcqr  = (unsigned short*)RA;
  unsigned short* nr    = (unsigned short*)RA;
  unsigned short* proj  = (unsigned short*)RB;
  unsigned short* hbuf  = (unsigned short*)RB;
  float* pairb = (float*)RD;
  unsigned short* slocb  = (unsigned short*)RE;
  unsigned short* rbufb  = (unsigned short*)RE;
  unsigned short* pinitb = (unsigned short*)(RE + (size_t)BH*S_*64*2);

  cvt_weights<<<dim3(3328), dim3(256), 0, stream>>>(Wa,Wb,Wql,Wqr,Wout,W1,W2, wcat,woutb,w1b,w2b);
  ln_gates<<<dim3(ROWS/4), dim3(256), 0, stream>>>(x, ng, nb, Wsd, bsd, Wpd, bpd, nbf, sdo, pdo);
  gemm128<0><<<dim3(128,16), dim3(256), 0, stream>>>(nbf, wcat, nullptr, nullptr, nullptr, nullptr, proj, 2048, 512);
  state_local<<<dim3(NCHUNK,BH), dim3(64), 0, stream>>>(proj, sdo, slocb, Sarr, sEnd);
  state_combine<<<dim3(BH), dim3(64), 0, stream>>>(sEnd, Sarr, sinit);
  pair_localm<<<dim3(NCHUNK,BH), dim3(128), 0, stream>>>(proj, pdo, slocb, Sarr, sinit, pairb, dprod);
  pair_combine<<<dim3(1024), dim3(256), 0, stream>>>(pairb, dprod, pinitb);
  pair_finalm<<<dim3(NCHUNK,BH), dim3(128), 0, stream>>>(proj, pdo, slocb, Sarr, sinit, pinitb, lcqr);
  gemm128<1><<<dim3(128,4), dim3(256), 0, stream>>>(lcqr, woutb, nullptr, x, nullptr, nullptr, rbufb, 512, 512);
  ln_plain<<<dim3(ROWS/4), dim3(256), 0, stream>>>(rbufb, fng, fnb, nr);
  gemm128<2><<<dim3(128,16), dim3(256), 0, stream>>>(nr, w1b, b1, nullptr, nullptr, nullptr, hbuf, 2048, 512);
  // FFN2: 256x128-tile 4-phase pipelined GEMM (nt=32, 1 block/CU, counted vmcnt)
  gemm_ffn2<<<dim3(64,4), dim3(512), 0, stream>>>(hbuf, w2b, b2, rbufb, out, 512, 2048);
}